// Round 8
// baseline (274.254 us; speedup 1.0000x reference)
//
#include <hip/hip_runtime.h>

typedef unsigned int u32;
typedef unsigned short u16;
typedef __attribute__((ext_vector_type(4))) float f32x4;
typedef __attribute__((ext_vector_type(2))) float f32x2;
typedef __attribute__((ext_vector_type(8))) short bf16x8;

static inline int cdiv(int a, int b) { return (a + b - 1) / b; }

#define NBKT 512
#define BSHIFT 7
#define BNODES 128
#define EPB2 16384  // edges per scatter block (LDS-staged)
#define CAP 5120    // per-bucket capacity; mean fill ~4096, +16 sigma headroom

// ---------- bf16 helpers ----------
__device__ inline u32 pk_bf16(float a, float b) {
  u32 ua = __builtin_bit_cast(u32, a);
  ua += 0x7fffu + ((ua >> 16) & 1u);
  u32 ub = __builtin_bit_cast(u32, b);
  ub += 0x7fffu + ((ub >> 16) & 1u);
  return (ua >> 16) | (ub & 0xffff0000u);
}

// ---------- fp32 -> fp8 e4m3 (4 elems/thread), both sides fused ----------
__global__ __launch_bounds__(256) void cvt_f8_k(const float* __restrict__ xs,
                                                const float* __restrict__ xt,
                                                int n4S, int n4T,
                                                u32* __restrict__ xsf8,
                                                u32* __restrict__ xtf8) {
  int i = blockIdx.x * 256 + threadIdx.x;
  const float* src;
  u32* dst;
  int q;
  if (i < n4S) {
    src = xs; dst = xsf8; q = i;
  } else {
    q = i - n4S;
    if (q >= n4T) return;
    src = xt; dst = xtf8;
  }
  float4 v = *reinterpret_cast<const float4*>(src + (size_t)q * 4);
  u32 p = 0;
  p = __builtin_amdgcn_cvt_pk_fp8_f32(v.x, v.y, p, false);
  p = __builtin_amdgcn_cvt_pk_fp8_f32(v.z, v.w, p, true);
  dst[q] = p;
}

// ---------- weights -> transposed bf16, packed buffer ----------
__global__ __launch_bounds__(256) void cvtW_k(const float* __restrict__ W1sl,
                                              const float* __restrict__ W1sr,
                                              const float* __restrict__ W1tl,
                                              const float* __restrict__ W1tr,
                                              const float* __restrict__ W2A_s,
                                              const float* __restrict__ W2B_s,
                                              const float* __restrict__ W2A_t,
                                              const float* __restrict__ W2B_t,
                                              u16* __restrict__ out) {
  int seg = blockIdx.x * 256 + threadIdx.x;  // 12288 total, 8 bf16 per seg
  if (seg >= 12288) return;
  const float* W;
  int ncol, base, local;
  if (seg < 8192) {
    int m = seg >> 11; local = seg & 2047; ncol = 128; base = m * 16384;
    W = m == 0 ? W1sl : m == 1 ? W1sr : m == 2 ? W1tl : W1tr;
  } else {
    int m = (seg - 8192) >> 10; local = (seg - 8192) & 1023; ncol = 64; base = 65536 + m * 8192;
    W = m == 0 ? W2A_s : m == 1 ? W2B_s : m == 2 ? W2A_t : W2B_t;
  }
  int col = local >> 4;
  int k0 = (local & 15) * 8;
  u16 tmp[8];
#pragma unroll
  for (int e = 0; e < 8; ++e) {
    float v = W[(size_t)(k0 + e) * ncol + col];
    tmp[e] = (u16)(pk_bf16(v, 0.f) & 0xffffu);
  }
  *reinterpret_cast<uint4*>(out + (size_t)base + col * 128 + k0) =
      *reinterpret_cast<uint4*>(tmp);
}

// ================= LDS-staged bucket scatter =================
// Block-local counting sort of EPB2 edges into 512 buckets (stage packs src<<16|dst),
// then run-contiguous copy-out: consecutive threads -> consecutive global addrs.

__global__ __launch_bounds__(512) void scatfuse2_k(const int* __restrict__ rowS,
                                                   const int* __restrict__ colS,
                                                   const int* __restrict__ rowT,
                                                   const int* __restrict__ colT,
                                                   int E, int nblk,
                                                   int* __restrict__ gcur,
                                                   u32* __restrict__ bktS,
                                                   u32* __restrict__ bktT) {
  __shared__ u32 stage[EPB2];
  __shared__ int h[NBKT], lstart[NBKT], lpos[NBKT], gbase[NBKT];
  int b = blockIdx.x;
  const int *row, *col;
  u32* bkt;
  int* gc;
  if (b < nblk) {
    row = rowS; col = colS; bkt = bktS; gc = gcur;
  } else {
    b -= nblk; row = rowT; col = colT; bkt = bktT; gc = gcur + NBKT;
  }
  int t = threadIdx.x;
  h[t] = 0;  // 512 threads == NBKT
  __syncthreads();
  int base = b * EPB2, end = min(base + EPB2, E);
  for (int i = base + t; i < end; i += 512) atomicAdd(&h[col[i] >> BSHIFT], 1);
  __syncthreads();
  lstart[t] = h[t];
  __syncthreads();
  for (int off = 1; off < NBKT; off <<= 1) {
    int x = (t >= off) ? lstart[t - off] : 0;
    __syncthreads();
    if (t >= off) lstart[t] += x;
    __syncthreads();
  }
  {
    int hc = h[t];
    int ls = lstart[t] - hc;
    lstart[t] = ls;
    lpos[t] = ls;
    gbase[t] = hc ? atomicAdd(&gc[t], hc) : 0;
  }
  __syncthreads();
  for (int i = base + t; i < end; i += 512) {
    int c = col[i];
    int p = atomicAdd(&lpos[c >> BSHIFT], 1);
    stage[p] = ((u32)row[i] << 16) | (u32)c;
  }
  __syncthreads();
  int total = end - base;
  for (int j = t; j < total; j += 512) {
    u32 v = stage[j];
    u32 d = v & 0xffffu;
    int bi = d >> BSHIFT;
    int gp = gbase[bi] + (j - lstart[bi]);
    bkt[(size_t)bi * CAP + gp] = ((v >> 16) << BSHIFT) | (d & (BNODES - 1));
  }
}

// ================= layer-1 agg: per-bucket LDS mini-CSR + fp8 gather =================
// Builds sorted src list in LDS, aggregates, then writes sorted csr back over the
// bucket region + packed st<<16|deg per node (consumed by agg64C with zero build cost).

__global__ __launch_bounds__(256) void agg128B_k(const u32* __restrict__ xs_f8,
                                                 const u32* __restrict__ xt_f8,
                                                 u32* __restrict__ bktS,
                                                 u32* __restrict__ bktT,
                                                 const int* __restrict__ gcur,
                                                 int NS, int NT,
                                                 u32* __restrict__ mean_s,
                                                 u32* __restrict__ mean_t,
                                                 u32* __restrict__ stdegS,
                                                 u32* __restrict__ stdegT) {
  __shared__ u32 srcs[CAP];
  __shared__ int cnt[BNODES], excl[BNODES], st[BNODES], cur[BNODES];
  int nbkS = (NS + BNODES - 1) >> BSHIFT;
  int b = blockIdx.x;
  const u32* xf8;
  u32 *bkt, *outm, *stdeg;
  int N, ec;
  if (b < nbkS) {
    xf8 = xt_f8; bkt = bktS + (size_t)b * CAP; ec = gcur[b]; outm = mean_s;
    stdeg = stdegS; N = NS;
  } else {
    b -= nbkS;
    xf8 = xs_f8; bkt = bktT + (size_t)b * CAP; ec = gcur[NBKT + b]; outm = mean_t;
    stdeg = stdegT; N = NT;
  }
  int node0 = b << BSHIFT;
  int t = threadIdx.x;
  if (t < BNODES) cnt[t] = 0;
  __syncthreads();
  for (int i = t; i < ec; i += 256) atomicAdd(&cnt[bkt[i] & (BNODES - 1)], 1);
  __syncthreads();
  if (t < BNODES) excl[t] = cnt[t];
  __syncthreads();
  for (int off = 1; off < BNODES; off <<= 1) {
    int x = 0;
    if (t < BNODES && t >= off) x = excl[t - off];
    __syncthreads();
    if (t < BNODES && t >= off) excl[t] += x;
    __syncthreads();
  }
  if (t < BNODES) {
    int s0 = excl[t] - cnt[t];
    st[t] = s0;
    cur[t] = s0;
  }
  __syncthreads();
  for (int i = t; i < ec; i += 256) {
    u32 p = bkt[i];
    int ps = atomicAdd(&cur[p & (BNODES - 1)], 1);
    srcs[ps] = p >> BSHIFT;
  }
  __syncthreads();
  // write back sorted csr (over the bucket region) + packed st|deg per node
  for (int i = t; i < ec; i += 256) bkt[i] = srcs[i];
  if (t < BNODES) {
    int node = node0 + t;
    if (node < N) stdeg[node] = ((u32)st[t] << 16) | (u32)cnt[t];
  }

  int gid = t >> 4, fl = t & 15;
  for (int n = gid; n < BNODES; n += 16) {
    int node = node0 + n;
    int s = st[n], deg = cnt[n], e = s + deg;
    f32x2 a0 = {0.f, 0.f}, a1 = {0.f, 0.f}, a2 = {0.f, 0.f}, a3 = {0.f, 0.f};
    int i = s;
    for (; i + 4 <= e; i += 4) {
      int c0 = srcs[i], c1 = srcs[i + 1], c2 = srcs[i + 2], c3 = srcs[i + 3];
      uint2 v0 = *reinterpret_cast<const uint2*>(xf8 + (size_t)c0 * 32 + fl * 2);
      uint2 v1 = *reinterpret_cast<const uint2*>(xf8 + (size_t)c1 * 32 + fl * 2);
      uint2 v2 = *reinterpret_cast<const uint2*>(xf8 + (size_t)c2 * 32 + fl * 2);
      uint2 v3 = *reinterpret_cast<const uint2*>(xf8 + (size_t)c3 * 32 + fl * 2);
      a0 += __builtin_amdgcn_cvt_pk_f32_fp8(v0.x, false);
      a1 += __builtin_amdgcn_cvt_pk_f32_fp8(v0.x, true);
      a2 += __builtin_amdgcn_cvt_pk_f32_fp8(v0.y, false);
      a3 += __builtin_amdgcn_cvt_pk_f32_fp8(v0.y, true);
      a0 += __builtin_amdgcn_cvt_pk_f32_fp8(v1.x, false);
      a1 += __builtin_amdgcn_cvt_pk_f32_fp8(v1.x, true);
      a2 += __builtin_amdgcn_cvt_pk_f32_fp8(v1.y, false);
      a3 += __builtin_amdgcn_cvt_pk_f32_fp8(v1.y, true);
      a0 += __builtin_amdgcn_cvt_pk_f32_fp8(v2.x, false);
      a1 += __builtin_amdgcn_cvt_pk_f32_fp8(v2.x, true);
      a2 += __builtin_amdgcn_cvt_pk_f32_fp8(v2.y, false);
      a3 += __builtin_amdgcn_cvt_pk_f32_fp8(v2.y, true);
      a0 += __builtin_amdgcn_cvt_pk_f32_fp8(v3.x, false);
      a1 += __builtin_amdgcn_cvt_pk_f32_fp8(v3.x, true);
      a2 += __builtin_amdgcn_cvt_pk_f32_fp8(v3.y, false);
      a3 += __builtin_amdgcn_cvt_pk_f32_fp8(v3.y, true);
    }
    for (; i < e; ++i) {
      int c0 = srcs[i];
      uint2 v0 = *reinterpret_cast<const uint2*>(xf8 + (size_t)c0 * 32 + fl * 2);
      a0 += __builtin_amdgcn_cvt_pk_f32_fp8(v0.x, false);
      a1 += __builtin_amdgcn_cvt_pk_f32_fp8(v0.x, true);
      a2 += __builtin_amdgcn_cvt_pk_f32_fp8(v0.y, false);
      a3 += __builtin_amdgcn_cvt_pk_f32_fp8(v0.y, true);
    }
    if (node < N) {
      float inv = deg > 0 ? 1.f / (float)deg : 0.f;
      uint4 p;
      p.x = pk_bf16(a0.x * inv, a0.y * inv);
      p.y = pk_bf16(a1.x * inv, a1.y * inv);
      p.z = pk_bf16(a2.x * inv, a2.y * inv);
      p.w = pk_bf16(a3.x * inv, a3.y * inv);
      *reinterpret_cast<uint4*>(outm + (size_t)node * 64 + fl * 4) = p;
    }
  }
}

// ================= layer-2 agg + epilogue: LDS-free, reads prebuilt csr/stdeg =================
// row = 64 fp8 = 16 u32, 1 u32/lane; z = mean + g + bias.

__global__ __launch_bounds__(256) void agg64C_k(const u32* __restrict__ hs_f8,
                                                const u32* __restrict__ ht_f8,
                                                const u32* __restrict__ csrS,
                                                const u32* __restrict__ csrT,
                                                const u32* __restrict__ stdegS,
                                                const u32* __restrict__ stdegT,
                                                int NS, int NT,
                                                const float* __restrict__ g_s,
                                                const float* __restrict__ g_t,
                                                const float* __restrict__ b2s,
                                                const float* __restrict__ b2t,
                                                float* __restrict__ z_s,
                                                float* __restrict__ z_t) {
  int nbkS = (NS + BNODES - 1) >> BSHIFT;
  int b = blockIdx.x;
  const u32 *hf8, *csr, *stdeg;
  const float *g, *bias;
  float* z;
  int N;
  if (b < nbkS) {
    hf8 = ht_f8; csr = csrS + (size_t)b * CAP; stdeg = stdegS;
    g = g_s; bias = b2s; z = z_s; N = NS;
  } else {
    b -= nbkS;
    hf8 = hs_f8; csr = csrT + (size_t)b * CAP; stdeg = stdegT;
    g = g_t; bias = b2t; z = z_t; N = NT;
  }
  int node0 = b << BSHIFT;
  int t = threadIdx.x;
  int gid = t >> 4, fl = t & 15;
  for (int n = gid; n < BNODES; n += 16) {
    int node = node0 + n;
    if (node >= N) continue;
    u32 sd = stdeg[node];
    int s = (int)(sd >> 16), deg = (int)(sd & 0xffffu), e = s + deg;
    f32x2 a0 = {0.f, 0.f}, a1 = {0.f, 0.f};
    int i = s;
    for (; i + 4 <= e; i += 4) {
      int c0 = csr[i], c1 = csr[i + 1], c2 = csr[i + 2], c3 = csr[i + 3];
      u32 v0 = hf8[(size_t)c0 * 16 + fl];
      u32 v1 = hf8[(size_t)c1 * 16 + fl];
      u32 v2 = hf8[(size_t)c2 * 16 + fl];
      u32 v3 = hf8[(size_t)c3 * 16 + fl];
      a0 += __builtin_amdgcn_cvt_pk_f32_fp8(v0, false);
      a1 += __builtin_amdgcn_cvt_pk_f32_fp8(v0, true);
      a0 += __builtin_amdgcn_cvt_pk_f32_fp8(v1, false);
      a1 += __builtin_amdgcn_cvt_pk_f32_fp8(v1, true);
      a0 += __builtin_amdgcn_cvt_pk_f32_fp8(v2, false);
      a1 += __builtin_amdgcn_cvt_pk_f32_fp8(v2, true);
      a0 += __builtin_amdgcn_cvt_pk_f32_fp8(v3, false);
      a1 += __builtin_amdgcn_cvt_pk_f32_fp8(v3, true);
    }
    for (; i < e; ++i) {
      u32 v0 = hf8[(size_t)csr[i] * 16 + fl];
      a0 += __builtin_amdgcn_cvt_pk_f32_fp8(v0, false);
      a1 += __builtin_amdgcn_cvt_pk_f32_fp8(v0, true);
    }
    float inv = deg > 0 ? 1.f / (float)deg : 0.f;
    float4 gv = *reinterpret_cast<const float4*>(g + (size_t)node * 64 + fl * 4);
    float4 bv = *reinterpret_cast<const float4*>(bias + fl * 4);
    float4 r;
    r.x = a0.x * inv + gv.x + bv.x;
    r.y = a0.y * inv + gv.y + bv.y;
    r.z = a1.x * inv + gv.z + bv.z;
    r.w = a1.y * inv + gv.w + bv.w;
    *reinterpret_cast<float4*>(z + (size_t)node * 64 + fl * 4) = r;
  }
}

// ---------------- layer-1 MFMA GEMM (dirs fused): xnew_bf16 = [mean|x]@[W0;W1]+bias ----------------

__global__ __launch_bounds__(256) void gemm1_dual_k(
    const u16* __restrict__ mean_s, const float* __restrict__ xs,
    const u16* __restrict__ mean_t, const float* __restrict__ xt,
    const u16* __restrict__ Wt_s0, const u16* __restrict__ Wt_s1,
    const u16* __restrict__ Wt_t0, const u16* __restrict__ Wt_t1,
    const float* __restrict__ b1s, const float* __restrict__ b1t,
    u16* __restrict__ xnew_s, u16* __restrict__ xnew_t, int NS, int NT) {
  int nb1 = (NS + 127) >> 7;
  int b = blockIdx.x;
  const u16 *A0, *Wt0, *Wt1;
  const float *X1, *bias;
  u16* out;
  int M, rowBase;
  if (b < nb1) {
    A0 = mean_s; X1 = xs; Wt0 = Wt_s0; Wt1 = Wt_s1; bias = b1s; out = xnew_s;
    M = NS; rowBase = b * 128;
  } else {
    A0 = mean_t; X1 = xt; Wt0 = Wt_t0; Wt1 = Wt_t1; bias = b1t; out = xnew_t;
    M = NT; rowBase = (b - nb1) * 128;
  }
  const int lane = threadIdx.x & 63;
  const int wid = threadIdx.x >> 6;
  const int r16 = lane & 15;
  const int kg = lane >> 4;
  rowBase += wid * 32;

  f32x4 acc[2][8];
#pragma unroll
  for (int i = 0; i < 2; ++i)
#pragma unroll
    for (int j = 0; j < 8; ++j) acc[i][j] = (f32x4){0.f, 0.f, 0.f, 0.f};

  const int r0 = min(rowBase + r16, M - 1);
  const int r1 = min(rowBase + 16 + r16, M - 1);

#pragma unroll
  for (int ch = 0; ch < 8; ++ch) {
    const int koff = (ch & 3) * 32 + kg * 8;
    bf16x8 x0, x1;
    if (ch < 4) {
      x0 = *reinterpret_cast<const bf16x8*>(A0 + (size_t)r0 * 128 + koff);
      x1 = *reinterpret_cast<const bf16x8*>(A0 + (size_t)r1 * 128 + koff);
    } else {
      float4 fa = *reinterpret_cast<const float4*>(X1 + (size_t)r0 * 128 + koff);
      float4 fb = *reinterpret_cast<const float4*>(X1 + (size_t)r0 * 128 + koff + 4);
      uint4 u0;
      u0.x = pk_bf16(fa.x, fa.y); u0.y = pk_bf16(fa.z, fa.w);
      u0.z = pk_bf16(fb.x, fb.y); u0.w = pk_bf16(fb.z, fb.w);
      x0 = __builtin_bit_cast(bf16x8, u0);
      float4 fc = *reinterpret_cast<const float4*>(X1 + (size_t)r1 * 128 + koff);
      float4 fd = *reinterpret_cast<const float4*>(X1 + (size_t)r1 * 128 + koff + 4);
      uint4 u1;
      u1.x = pk_bf16(fc.x, fc.y); u1.y = pk_bf16(fc.z, fc.w);
      u1.z = pk_bf16(fd.x, fd.y); u1.w = pk_bf16(fd.z, fd.w);
      x1 = __builtin_bit_cast(bf16x8, u1);
    }
    const u16* Wt = (ch < 4) ? Wt0 : Wt1;
#pragma unroll
    for (int cb = 0; cb < 8; ++cb) {
      bf16x8 w = *reinterpret_cast<const bf16x8*>(Wt + (size_t)(cb * 16 + r16) * 128 + koff);
      acc[0][cb] = __builtin_amdgcn_mfma_f32_16x16x32_bf16(w, x0, acc[0][cb], 0, 0, 0);
      acc[1][cb] = __builtin_amdgcn_mfma_f32_16x16x32_bf16(w, x1, acc[1][cb], 0, 0, 0);
    }
  }

#pragma unroll
  for (int cb = 0; cb < 8; ++cb) {
    float4 bv = *reinterpret_cast<const float4*>(bias + cb * 16 + kg * 4);
#pragma unroll
    for (int rb = 0; rb < 2; ++rb) {
      int row = rowBase + rb * 16 + r16;
      if (row < M) {
        f32x4 a = acc[rb][cb];
        uint2 p;
        p.x = pk_bf16(a[0] + bv.x, a[1] + bv.y);
        p.y = pk_bf16(a[2] + bv.z, a[3] + bv.w);
        *reinterpret_cast<uint2*>(out + (size_t)row * 128 + cb * 16 + kg * 4) = p;
      }
    }
  }
}

// ---------------- layer-2 MFMA GEMM (dirs fused): h_fp8 = X@Wa, g_f32 = X@Wb ----------------

__global__ __launch_bounds__(256) void gemm2_dual_k(
    const u16* __restrict__ xnew_s, const u16* __restrict__ xnew_t,
    const u16* __restrict__ WtA_s, const u16* __restrict__ WtB_s,
    const u16* __restrict__ WtA_t, const u16* __restrict__ WtB_t,
    u32* __restrict__ hs_f8, u32* __restrict__ ht_f8,
    float* __restrict__ g_s, float* __restrict__ g_t, int NS, int NT) {
  int nb1 = (NS + 127) >> 7;
  int b = blockIdx.x;
  const u16 *X, *WtA, *WtB;
  u32* h;
  float* g;
  int M, rowBase;
  if (b < nb1) {
    X = xnew_s; WtA = WtA_s; WtB = WtB_s; h = hs_f8; g = g_s; M = NS; rowBase = b * 128;
  } else {
    X = xnew_t; WtA = WtA_t; WtB = WtB_t; h = ht_f8; g = g_t; M = NT;
    rowBase = (b - nb1) * 128;
  }
  const int lane = threadIdx.x & 63;
  const int wid = threadIdx.x >> 6;
  const int r16 = lane & 15;
  const int kg = lane >> 4;
  rowBase += wid * 32;

  f32x4 acc[2][8];
#pragma unroll
  for (int i = 0; i < 2; ++i)
#pragma unroll
    for (int j = 0; j < 8; ++j) acc[i][j] = (f32x4){0.f, 0.f, 0.f, 0.f};

  const int r0 = min(rowBase + r16, M - 1);
  const int r1 = min(rowBase + 16 + r16, M - 1);

#pragma unroll
  for (int ch = 0; ch < 4; ++ch) {
    const int koff = ch * 32 + kg * 8;
    bf16x8 x0 = *reinterpret_cast<const bf16x8*>(X + (size_t)r0 * 128 + koff);
    bf16x8 x1 = *reinterpret_cast<const bf16x8*>(X + (size_t)r1 * 128 + koff);
#pragma unroll
    for (int cb = 0; cb < 8; ++cb) {
      const u16* Wt = (cb < 4) ? WtA : WtB;
      bf16x8 w = *reinterpret_cast<const bf16x8*>(Wt + (size_t)((cb & 3) * 16 + r16) * 128 + koff);
      acc[0][cb] = __builtin_amdgcn_mfma_f32_16x16x32_bf16(w, x0, acc[0][cb], 0, 0, 0);
      acc[1][cb] = __builtin_amdgcn_mfma_f32_16x16x32_bf16(w, x1, acc[1][cb], 0, 0, 0);
    }
  }

#pragma unroll
  for (int cb = 0; cb < 8; ++cb) {
#pragma unroll
    for (int rb = 0; rb < 2; ++rb) {
      int row = rowBase + rb * 16 + r16;
      if (row < M) {
        f32x4 a = acc[rb][cb];
        if (cb < 4) {
          u32 p = 0;
          p = __builtin_amdgcn_cvt_pk_fp8_f32(a[0], a[1], p, false);
          p = __builtin_amdgcn_cvt_pk_fp8_f32(a[2], a[3], p, true);
          h[(size_t)row * 16 + cb * 4 + kg] = p;
        } else {
          *reinterpret_cast<f32x4*>(g + (size_t)row * 64 + (cb - 4) * 16 + kg * 4) = a;
        }
      }
    }
  }
}

// ---------------- launch ----------------

extern "C" void kernel_launch(void* const* d_in, const int* in_sizes, int n_in,
                              void* d_out, int out_size, void* d_ws, size_t ws_size,
                              hipStream_t stream) {
  const float* x_s = (const float*)d_in[0];
  const float* x_t = (const float*)d_in[1];
  const int* s2t = (const int*)d_in[2];
  const int* t2s = (const int*)d_in[3];
  const float* W1s_l = (const float*)d_in[4];
  const float* W1s_r = (const float*)d_in[5];
  const float* b1s = (const float*)d_in[6];
  const float* W1t_l = (const float*)d_in[7];
  const float* W1t_r = (const float*)d_in[8];
  const float* b1t = (const float*)d_in[9];
  const float* W2s_l = (const float*)d_in[10];
  const float* W2s_r = (const float*)d_in[11];
  const float* b2s = (const float*)d_in[12];
  const float* W2t_l = (const float*)d_in[13];
  const float* W2t_r = (const float*)d_in[14];
  const float* b2t = (const float*)d_in[15];

  const int NS = in_sizes[0] / 128;
  const int NT = in_sizes[1] / 128;
  const int E = in_sizes[2] / 2;

  char* ws = (char*)d_ws;
  size_t off = 0;
  auto alloc = [&](size_t bytes) -> void* {
    void* p = ws + off;
    off = (off + bytes + 255) & ~(size_t)255;
    return p;
  };

  const int nbkS = cdiv(NS, BNODES);
  const int nbkT = cdiv(NT, BNODES);
  const int nblk2 = cdiv(E, EPB2);

  int* gcur = (int*)alloc(2 * NBKT * 4);
  u16* Wt = (u16*)alloc(98304 * 2);
  u32* bktS = (u32*)alloc((size_t)nbkS * CAP * 4);
  u32* bktT = (u32*)alloc((size_t)nbkT * CAP * 4);
  u32* stdegS = (u32*)alloc((size_t)NS * 4);
  u32* stdegT = (u32*)alloc((size_t)NT * 4);

  // R2 ((NS+NT)*512 B): head [0,384B/node) = mean_bf -> h_f8/g; tail [384,512) = fp8 x
  char* R2 = (char*)alloc((size_t)(NS + NT) * 512);
  u16* xnew_s = (u16*)alloc((size_t)(NS + NT) * 256);  // bf16 [*][128]
  u16* xnew_t = xnew_s + (size_t)NS * 128;

  u16* mean_s = (u16*)R2;  // [NS][128] bf16
  u16* mean_t = mean_s + (size_t)NS * 128;
  u32* hs_f8 = (u32*)R2;   // [NS][16] u32 (64 fp8)
  u32* ht_f8 = hs_f8 + (size_t)NS * 16;
  float* g_s = (float*)(ht_f8 + (size_t)NT * 16);
  float* g_t = g_s + (size_t)NS * 64;

  u32* xs_f8 = (u32*)(R2 + (size_t)(NS + NT) * 384);  // [NS][32] u32
  u32* xt_f8 = xs_f8 + (size_t)NS * 32;

  u16* Wt1s_l = Wt;
  u16* Wt1s_r = Wt + 16384;
  u16* Wt1t_l = Wt + 32768;
  u16* Wt1t_r = Wt + 49152;
  u16* Wt2A_s = Wt + 65536;  // W2t_l^T (h_s)
  u16* Wt2B_s = Wt + 73728;  // W2s_r^T (g_s)
  u16* Wt2A_t = Wt + 81920;  // W2s_l^T (h_t)
  u16* Wt2B_t = Wt + 90112;  // W2t_r^T (g_t)

  float* z_s = (float*)d_out;
  float* z_t = (float*)d_out + (size_t)NS * 64;

  // conversions + bucket-cursor reset
  cvt_f8_k<<<cdiv(NS * 32 + NT * 32, 256), 256, 0, stream>>>(
      x_s, x_t, NS * 32, NT * 32, xs_f8, xt_f8);
  cvtW_k<<<48, 256, 0, stream>>>(W1s_l, W1s_r, W1t_l, W1t_r,
                                 W2t_l, W2s_r, W2s_l, W2t_r, Wt);
  hipMemsetAsync(gcur, 0, 2 * NBKT * 4, stream);

  // LDS-staged bucket scatter, both directions
  scatfuse2_k<<<2 * nblk2, 512, 0, stream>>>(t2s, t2s + E, s2t, s2t + E, E, nblk2,
                                             gcur, bktS, bktT);

  // ----- layer 1 -----
  agg128B_k<<<nbkS + nbkT, 256, 0, stream>>>(xs_f8, xt_f8, bktS, bktT, gcur,
                                             NS, NT, (u32*)mean_s, (u32*)mean_t,
                                             stdegS, stdegT);
  gemm1_dual_k<<<cdiv(NS, 128) + cdiv(NT, 128), 256, 0, stream>>>(
      mean_s, x_s, mean_t, x_t, Wt1s_l, Wt1s_r, Wt1t_l, Wt1t_r,
      b1s, b1t, xnew_s, xnew_t, NS, NT);

  // ----- layer 2 (transform-first) -----
  gemm2_dual_k<<<cdiv(NS, 128) + cdiv(NT, 128), 256, 0, stream>>>(
      xnew_s, xnew_t, Wt2A_s, Wt2B_s, Wt2A_t, Wt2B_t, hs_f8, ht_f8, g_s, g_t, NS, NT);
  agg64C_k<<<nbkS + nbkT, 256, 0, stream>>>(hs_f8, ht_f8, bktS, bktT, stdegS, stdegT,
                                            NS, NT, g_s, g_t, b2s, b2t, z_s, z_t);
}

// Round 9
// 233.605 us; speedup vs baseline: 1.1740x; 1.1740x over previous
//
#include <hip/hip_runtime.h>

typedef unsigned int u32;
typedef unsigned short u16;
typedef __attribute__((ext_vector_type(4))) float f32x4;
typedef __attribute__((ext_vector_type(2))) float f32x2;
typedef __attribute__((ext_vector_type(8))) short bf16x8;

static inline int cdiv(int a, int b) { return (a + b - 1) / b; }

#define NBKT 512
#define BSHIFT 7
#define BNODES 128
#define EPB2 16384  // edges per scatter block (LDS-staged)
#define CAP 5120    // per-bucket capacity; mean fill ~4096, +16 sigma headroom

// ---------- bf16 helpers ----------
__device__ inline u32 pk_bf16(float a, float b) {
  u32 ua = __builtin_bit_cast(u32, a);
  ua += 0x7fffu + ((ua >> 16) & 1u);
  u32 ub = __builtin_bit_cast(u32, b);
  ub += 0x7fffu + ((ub >> 16) & 1u);
  return (ua >> 16) | (ub & 0xffff0000u);
}

// ---------- fp32 -> fp8 e4m3 (4 elems/thread), both sides fused ----------
__global__ __launch_bounds__(256) void cvt_f8_k(const float* __restrict__ xs,
                                                const float* __restrict__ xt,
                                                int n4S, int n4T,
                                                u32* __restrict__ xsf8,
                                                u32* __restrict__ xtf8) {
  int i = blockIdx.x * 256 + threadIdx.x;
  const float* src;
  u32* dst;
  int q;
  if (i < n4S) {
    src = xs; dst = xsf8; q = i;
  } else {
    q = i - n4S;
    if (q >= n4T) return;
    src = xt; dst = xtf8;
  }
  float4 v = *reinterpret_cast<const float4*>(src + (size_t)q * 4);
  u32 p = 0;
  p = __builtin_amdgcn_cvt_pk_fp8_f32(v.x, v.y, p, false);
  p = __builtin_amdgcn_cvt_pk_fp8_f32(v.z, v.w, p, true);
  dst[q] = p;
}

// ---------- weights -> transposed bf16, packed buffer ----------
__global__ __launch_bounds__(256) void cvtW_k(const float* __restrict__ W1sl,
                                              const float* __restrict__ W1sr,
                                              const float* __restrict__ W1tl,
                                              const float* __restrict__ W1tr,
                                              const float* __restrict__ W2A_s,
                                              const float* __restrict__ W2B_s,
                                              const float* __restrict__ W2A_t,
                                              const float* __restrict__ W2B_t,
                                              u16* __restrict__ out) {
  int seg = blockIdx.x * 256 + threadIdx.x;  // 12288 total, 8 bf16 per seg
  if (seg >= 12288) return;
  const float* W;
  int ncol, base, local;
  if (seg < 8192) {
    int m = seg >> 11; local = seg & 2047; ncol = 128; base = m * 16384;
    W = m == 0 ? W1sl : m == 1 ? W1sr : m == 2 ? W1tl : W1tr;
  } else {
    int m = (seg - 8192) >> 10; local = (seg - 8192) & 1023; ncol = 64; base = 65536 + m * 8192;
    W = m == 0 ? W2A_s : m == 1 ? W2B_s : m == 2 ? W2A_t : W2B_t;
  }
  int col = local >> 4;
  int k0 = (local & 15) * 8;
  u16 tmp[8];
#pragma unroll
  for (int e = 0; e < 8; ++e) {
    float v = W[(size_t)(k0 + e) * ncol + col];
    tmp[e] = (u16)(pk_bf16(v, 0.f) & 0xffffu);
  }
  *reinterpret_cast<uint4*>(out + (size_t)base + col * 128 + k0) =
      *reinterpret_cast<uint4*>(tmp);
}

// ================= LDS-staged bucket scatter =================

__global__ __launch_bounds__(512) void scatfuse2_k(const int* __restrict__ rowS,
                                                   const int* __restrict__ colS,
                                                   const int* __restrict__ rowT,
                                                   const int* __restrict__ colT,
                                                   int E, int nblk,
                                                   int* __restrict__ gcur,
                                                   u32* __restrict__ bktS,
                                                   u32* __restrict__ bktT) {
  __shared__ u32 stage[EPB2];
  __shared__ int h[NBKT], lstart[NBKT], lpos[NBKT], gbase[NBKT];
  int b = blockIdx.x;
  const int *row, *col;
  u32* bkt;
  int* gc;
  if (b < nblk) {
    row = rowS; col = colS; bkt = bktS; gc = gcur;
  } else {
    b -= nblk; row = rowT; col = colT; bkt = bktT; gc = gcur + NBKT;
  }
  int t = threadIdx.x;
  h[t] = 0;  // 512 threads == NBKT
  __syncthreads();
  int base = b * EPB2, end = min(base + EPB2, E);
  for (int i = base + t; i < end; i += 512) atomicAdd(&h[col[i] >> BSHIFT], 1);
  __syncthreads();
  lstart[t] = h[t];
  __syncthreads();
  for (int off = 1; off < NBKT; off <<= 1) {
    int x = (t >= off) ? lstart[t - off] : 0;
    __syncthreads();
    if (t >= off) lstart[t] += x;
    __syncthreads();
  }
  {
    int hc = h[t];
    int ls = lstart[t] - hc;
    lstart[t] = ls;
    lpos[t] = ls;
    gbase[t] = hc ? atomicAdd(&gc[t], hc) : 0;
  }
  __syncthreads();
  for (int i = base + t; i < end; i += 512) {
    int c = col[i];
    int p = atomicAdd(&lpos[c >> BSHIFT], 1);
    stage[p] = ((u32)row[i] << 16) | (u32)c;
  }
  __syncthreads();
  int total = end - base;
  for (int j = t; j < total; j += 512) {
    u32 v = stage[j];
    u32 d = v & 0xffffu;
    int bi = d >> BSHIFT;
    int gp = gbase[bi] + (j - lstart[bi]);
    bkt[(size_t)bi * CAP + gp] = ((v >> 16) << BSHIFT) | (d & (BNODES - 1));
  }
}

// ================= per-bucket sort: bkt -> sorted csr (in place) + stdeg =================

__global__ __launch_bounds__(256) void sortb_k(u32* __restrict__ bktS,
                                               u32* __restrict__ bktT,
                                               const int* __restrict__ gcur,
                                               int NS, int NT,
                                               u32* __restrict__ stdegS,
                                               u32* __restrict__ stdegT) {
  __shared__ u32 srcs[CAP];
  __shared__ int cnt[BNODES], excl[BNODES], st[BNODES], cur[BNODES];
  int nbkS = (NS + BNODES - 1) >> BSHIFT;
  int b = blockIdx.x;
  u32 *bkt, *stdeg;
  int N, ec;
  if (b < nbkS) {
    bkt = bktS + (size_t)b * CAP; ec = gcur[b]; stdeg = stdegS; N = NS;
  } else {
    b -= nbkS;
    bkt = bktT + (size_t)b * CAP; ec = gcur[NBKT + b]; stdeg = stdegT; N = NT;
  }
  int node0 = b << BSHIFT;
  int t = threadIdx.x;
  if (t < BNODES) cnt[t] = 0;
  __syncthreads();
  for (int i = t; i < ec; i += 256) atomicAdd(&cnt[bkt[i] & (BNODES - 1)], 1);
  __syncthreads();
  if (t < BNODES) excl[t] = cnt[t];
  __syncthreads();
  for (int off = 1; off < BNODES; off <<= 1) {
    int x = 0;
    if (t < BNODES && t >= off) x = excl[t - off];
    __syncthreads();
    if (t < BNODES && t >= off) excl[t] += x;
    __syncthreads();
  }
  if (t < BNODES) {
    int s0 = excl[t] - cnt[t];
    st[t] = s0;
    cur[t] = s0;
  }
  __syncthreads();
  for (int i = t; i < ec; i += 256) {
    u32 p = bkt[i];
    int ps = atomicAdd(&cur[p & (BNODES - 1)], 1);
    srcs[ps] = p >> BSHIFT;
  }
  __syncthreads();
  for (int i = t; i < ec; i += 256) bkt[i] = srcs[i];
  if (t < BNODES) {
    int node = node0 + t;
    if (node < N) stdeg[node] = ((u32)st[t] << 16) | (u32)cnt[t];
  }
}

// ================= layer-1 gather: one node per 16-lane group, high occupancy =================
// row = 128 fp8 = 32 u32; lane loads uint2 (8 fp8). 16 nodes per block.

__global__ __launch_bounds__(256) void agg128D_k(const u32* __restrict__ xs_f8,
                                                 const u32* __restrict__ xt_f8,
                                                 const u32* __restrict__ bktS,
                                                 const u32* __restrict__ bktT,
                                                 const u32* __restrict__ stdegS,
                                                 const u32* __restrict__ stdegT,
                                                 int NS, int NT,
                                                 u32* __restrict__ mean_s,
                                                 u32* __restrict__ mean_t) {
  int nbS = (NS + 15) >> 4;
  int b = blockIdx.x;
  int gid = threadIdx.x >> 4, fl = threadIdx.x & 15;
  const u32 *xf8, *bkt, *stdeg;
  u32* outm;
  int N, node;
  if (b < nbS) {
    xf8 = xt_f8; bkt = bktS; stdeg = stdegS; outm = mean_s; N = NS;
    node = b * 16 + gid;
  } else {
    xf8 = xs_f8; bkt = bktT; stdeg = stdegT; outm = mean_t; N = NT;
    node = (b - nbS) * 16 + gid;
  }
  if (node >= N) return;
  u32 sd = stdeg[node];
  int deg = (int)(sd & 0xffffu);
  const u32* csr = bkt + (size_t)(node >> BSHIFT) * CAP + (sd >> 16);
  f32x2 a0 = {0.f, 0.f}, a1 = {0.f, 0.f}, a2 = {0.f, 0.f}, a3 = {0.f, 0.f};
  int i = 0;
  for (; i + 4 <= deg; i += 4) {
    int c0 = csr[i], c1 = csr[i + 1], c2 = csr[i + 2], c3 = csr[i + 3];
    uint2 v0 = *reinterpret_cast<const uint2*>(xf8 + (size_t)c0 * 32 + fl * 2);
    uint2 v1 = *reinterpret_cast<const uint2*>(xf8 + (size_t)c1 * 32 + fl * 2);
    uint2 v2 = *reinterpret_cast<const uint2*>(xf8 + (size_t)c2 * 32 + fl * 2);
    uint2 v3 = *reinterpret_cast<const uint2*>(xf8 + (size_t)c3 * 32 + fl * 2);
    a0 += __builtin_amdgcn_cvt_pk_f32_fp8(v0.x, false);
    a1 += __builtin_amdgcn_cvt_pk_f32_fp8(v0.x, true);
    a2 += __builtin_amdgcn_cvt_pk_f32_fp8(v0.y, false);
    a3 += __builtin_amdgcn_cvt_pk_f32_fp8(v0.y, true);
    a0 += __builtin_amdgcn_cvt_pk_f32_fp8(v1.x, false);
    a1 += __builtin_amdgcn_cvt_pk_f32_fp8(v1.x, true);
    a2 += __builtin_amdgcn_cvt_pk_f32_fp8(v1.y, false);
    a3 += __builtin_amdgcn_cvt_pk_f32_fp8(v1.y, true);
    a0 += __builtin_amdgcn_cvt_pk_f32_fp8(v2.x, false);
    a1 += __builtin_amdgcn_cvt_pk_f32_fp8(v2.x, true);
    a2 += __builtin_amdgcn_cvt_pk_f32_fp8(v2.y, false);
    a3 += __builtin_amdgcn_cvt_pk_f32_fp8(v2.y, true);
    a0 += __builtin_amdgcn_cvt_pk_f32_fp8(v3.x, false);
    a1 += __builtin_amdgcn_cvt_pk_f32_fp8(v3.x, true);
    a2 += __builtin_amdgcn_cvt_pk_f32_fp8(v3.y, false);
    a3 += __builtin_amdgcn_cvt_pk_f32_fp8(v3.y, true);
  }
  for (; i < deg; ++i) {
    int c0 = csr[i];
    uint2 v0 = *reinterpret_cast<const uint2*>(xf8 + (size_t)c0 * 32 + fl * 2);
    a0 += __builtin_amdgcn_cvt_pk_f32_fp8(v0.x, false);
    a1 += __builtin_amdgcn_cvt_pk_f32_fp8(v0.x, true);
    a2 += __builtin_amdgcn_cvt_pk_f32_fp8(v0.y, false);
    a3 += __builtin_amdgcn_cvt_pk_f32_fp8(v0.y, true);
  }
  float inv = deg > 0 ? 1.f / (float)deg : 0.f;
  uint4 p;
  p.x = pk_bf16(a0.x * inv, a0.y * inv);
  p.y = pk_bf16(a1.x * inv, a1.y * inv);
  p.z = pk_bf16(a2.x * inv, a2.y * inv);
  p.w = pk_bf16(a3.x * inv, a3.y * inv);
  *reinterpret_cast<uint4*>(outm + (size_t)node * 64 + fl * 4) = p;
}

// ================= layer-2 gather + epilogue: one node per 16-lane group =================
// row = 64 fp8 = 16 u32; lane loads 1 u32. z = mean + g + bias.

__global__ __launch_bounds__(256) void agg64D_k(const u32* __restrict__ hs_f8,
                                                const u32* __restrict__ ht_f8,
                                                const u32* __restrict__ bktS,
                                                const u32* __restrict__ bktT,
                                                const u32* __restrict__ stdegS,
                                                const u32* __restrict__ stdegT,
                                                int NS, int NT,
                                                const float* __restrict__ g_s,
                                                const float* __restrict__ g_t,
                                                const float* __restrict__ b2s,
                                                const float* __restrict__ b2t,
                                                float* __restrict__ z_s,
                                                float* __restrict__ z_t) {
  int nbS = (NS + 15) >> 4;
  int b = blockIdx.x;
  int gid = threadIdx.x >> 4, fl = threadIdx.x & 15;
  const u32 *hf8, *bkt, *stdeg;
  const float *g, *bias;
  float* z;
  int N, node;
  if (b < nbS) {
    hf8 = ht_f8; bkt = bktS; stdeg = stdegS; g = g_s; bias = b2s; z = z_s; N = NS;
    node = b * 16 + gid;
  } else {
    hf8 = hs_f8; bkt = bktT; stdeg = stdegT; g = g_t; bias = b2t; z = z_t; N = NT;
    node = (b - nbS) * 16 + gid;
  }
  if (node >= N) return;
  u32 sd = stdeg[node];
  int deg = (int)(sd & 0xffffu);
  const u32* csr = bkt + (size_t)(node >> BSHIFT) * CAP + (sd >> 16);
  f32x2 a0 = {0.f, 0.f}, a1 = {0.f, 0.f};
  int i = 0;
  for (; i + 4 <= deg; i += 4) {
    int c0 = csr[i], c1 = csr[i + 1], c2 = csr[i + 2], c3 = csr[i + 3];
    u32 v0 = hf8[(size_t)c0 * 16 + fl];
    u32 v1 = hf8[(size_t)c1 * 16 + fl];
    u32 v2 = hf8[(size_t)c2 * 16 + fl];
    u32 v3 = hf8[(size_t)c3 * 16 + fl];
    a0 += __builtin_amdgcn_cvt_pk_f32_fp8(v0, false);
    a1 += __builtin_amdgcn_cvt_pk_f32_fp8(v0, true);
    a0 += __builtin_amdgcn_cvt_pk_f32_fp8(v1, false);
    a1 += __builtin_amdgcn_cvt_pk_f32_fp8(v1, true);
    a0 += __builtin_amdgcn_cvt_pk_f32_fp8(v2, false);
    a1 += __builtin_amdgcn_cvt_pk_f32_fp8(v2, true);
    a0 += __builtin_amdgcn_cvt_pk_f32_fp8(v3, false);
    a1 += __builtin_amdgcn_cvt_pk_f32_fp8(v3, true);
  }
  for (; i < deg; ++i) {
    u32 v0 = hf8[(size_t)csr[i] * 16 + fl];
    a0 += __builtin_amdgcn_cvt_pk_f32_fp8(v0, false);
    a1 += __builtin_amdgcn_cvt_pk_f32_fp8(v0, true);
  }
  float inv = deg > 0 ? 1.f / (float)deg : 0.f;
  float4 gv = *reinterpret_cast<const float4*>(g + (size_t)node * 64 + fl * 4);
  float4 bv = *reinterpret_cast<const float4*>(bias + fl * 4);
  float4 r;
  r.x = a0.x * inv + gv.x + bv.x;
  r.y = a0.y * inv + gv.y + bv.y;
  r.z = a1.x * inv + gv.z + bv.z;
  r.w = a1.y * inv + gv.w + bv.w;
  *reinterpret_cast<float4*>(z + (size_t)node * 64 + fl * 4) = r;
}

// ---------------- layer-1 MFMA GEMM (dirs fused): xnew_bf16 = [mean|x]@[W0;W1]+bias ----------------

__global__ __launch_bounds__(256) void gemm1_dual_k(
    const u16* __restrict__ mean_s, const float* __restrict__ xs,
    const u16* __restrict__ mean_t, const float* __restrict__ xt,
    const u16* __restrict__ Wt_s0, const u16* __restrict__ Wt_s1,
    const u16* __restrict__ Wt_t0, const u16* __restrict__ Wt_t1,
    const float* __restrict__ b1s, const float* __restrict__ b1t,
    u16* __restrict__ xnew_s, u16* __restrict__ xnew_t, int NS, int NT) {
  int nb1 = (NS + 127) >> 7;
  int b = blockIdx.x;
  const u16 *A0, *Wt0, *Wt1;
  const float *X1, *bias;
  u16* out;
  int M, rowBase;
  if (b < nb1) {
    A0 = mean_s; X1 = xs; Wt0 = Wt_s0; Wt1 = Wt_s1; bias = b1s; out = xnew_s;
    M = NS; rowBase = b * 128;
  } else {
    A0 = mean_t; X1 = xt; Wt0 = Wt_t0; Wt1 = Wt_t1; bias = b1t; out = xnew_t;
    M = NT; rowBase = (b - nb1) * 128;
  }
  const int lane = threadIdx.x & 63;
  const int wid = threadIdx.x >> 6;
  const int r16 = lane & 15;
  const int kg = lane >> 4;
  rowBase += wid * 32;

  f32x4 acc[2][8];
#pragma unroll
  for (int i = 0; i < 2; ++i)
#pragma unroll
    for (int j = 0; j < 8; ++j) acc[i][j] = (f32x4){0.f, 0.f, 0.f, 0.f};

  const int r0 = min(rowBase + r16, M - 1);
  const int r1 = min(rowBase + 16 + r16, M - 1);

#pragma unroll
  for (int ch = 0; ch < 8; ++ch) {
    const int koff = (ch & 3) * 32 + kg * 8;
    bf16x8 x0, x1;
    if (ch < 4) {
      x0 = *reinterpret_cast<const bf16x8*>(A0 + (size_t)r0 * 128 + koff);
      x1 = *reinterpret_cast<const bf16x8*>(A0 + (size_t)r1 * 128 + koff);
    } else {
      float4 fa = *reinterpret_cast<const float4*>(X1 + (size_t)r0 * 128 + koff);
      float4 fb = *reinterpret_cast<const float4*>(X1 + (size_t)r0 * 128 + koff + 4);
      uint4 u0;
      u0.x = pk_bf16(fa.x, fa.y); u0.y = pk_bf16(fa.z, fa.w);
      u0.z = pk_bf16(fb.x, fb.y); u0.w = pk_bf16(fb.z, fb.w);
      x0 = __builtin_bit_cast(bf16x8, u0);
      float4 fc = *reinterpret_cast<const float4*>(X1 + (size_t)r1 * 128 + koff);
      float4 fd = *reinterpret_cast<const float4*>(X1 + (size_t)r1 * 128 + koff + 4);
      uint4 u1;
      u1.x = pk_bf16(fc.x, fc.y); u1.y = pk_bf16(fc.z, fc.w);
      u1.z = pk_bf16(fd.x, fd.y); u1.w = pk_bf16(fd.z, fd.w);
      x1 = __builtin_bit_cast(bf16x8, u1);
    }
    const u16* Wt = (ch < 4) ? Wt0 : Wt1;
#pragma unroll
    for (int cb = 0; cb < 8; ++cb) {
      bf16x8 w = *reinterpret_cast<const bf16x8*>(Wt + (size_t)(cb * 16 + r16) * 128 + koff);
      acc[0][cb] = __builtin_amdgcn_mfma_f32_16x16x32_bf16(w, x0, acc[0][cb], 0, 0, 0);
      acc[1][cb] = __builtin_amdgcn_mfma_f32_16x16x32_bf16(w, x1, acc[1][cb], 0, 0, 0);
    }
  }

#pragma unroll
  for (int cb = 0; cb < 8; ++cb) {
    float4 bv = *reinterpret_cast<const float4*>(bias + cb * 16 + kg * 4);
#pragma unroll
    for (int rb = 0; rb < 2; ++rb) {
      int row = rowBase + rb * 16 + r16;
      if (row < M) {
        f32x4 a = acc[rb][cb];
        uint2 p;
        p.x = pk_bf16(a[0] + bv.x, a[1] + bv.y);
        p.y = pk_bf16(a[2] + bv.z, a[3] + bv.w);
        *reinterpret_cast<uint2*>(out + (size_t)row * 128 + cb * 16 + kg * 4) = p;
      }
    }
  }
}

// ---------------- layer-2 MFMA GEMM (dirs fused): h_fp8 = X@Wa, g_f32 = X@Wb ----------------

__global__ __launch_bounds__(256) void gemm2_dual_k(
    const u16* __restrict__ xnew_s, const u16* __restrict__ xnew_t,
    const u16* __restrict__ WtA_s, const u16* __restrict__ WtB_s,
    const u16* __restrict__ WtA_t, const u16* __restrict__ WtB_t,
    u32* __restrict__ hs_f8, u32* __restrict__ ht_f8,
    float* __restrict__ g_s, float* __restrict__ g_t, int NS, int NT) {
  int nb1 = (NS + 127) >> 7;
  int b = blockIdx.x;
  const u16 *X, *WtA, *WtB;
  u32* h;
  float* g;
  int M, rowBase;
  if (b < nb1) {
    X = xnew_s; WtA = WtA_s; WtB = WtB_s; h = hs_f8; g = g_s; M = NS; rowBase = b * 128;
  } else {
    X = xnew_t; WtA = WtA_t; WtB = WtB_t; h = ht_f8; g = g_t; M = NT;
    rowBase = (b - nb1) * 128;
  }
  const int lane = threadIdx.x & 63;
  const int wid = threadIdx.x >> 6;
  const int r16 = lane & 15;
  const int kg = lane >> 4;
  rowBase += wid * 32;

  f32x4 acc[2][8];
#pragma unroll
  for (int i = 0; i < 2; ++i)
#pragma unroll
    for (int j = 0; j < 8; ++j) acc[i][j] = (f32x4){0.f, 0.f, 0.f, 0.f};

  const int r0 = min(rowBase + r16, M - 1);
  const int r1 = min(rowBase + 16 + r16, M - 1);

#pragma unroll
  for (int ch = 0; ch < 4; ++ch) {
    const int koff = ch * 32 + kg * 8;
    bf16x8 x0 = *reinterpret_cast<const bf16x8*>(X + (size_t)r0 * 128 + koff);
    bf16x8 x1 = *reinterpret_cast<const bf16x8*>(X + (size_t)r1 * 128 + koff);
#pragma unroll
    for (int cb = 0; cb < 8; ++cb) {
      const u16* Wt = (cb < 4) ? WtA : WtB;
      bf16x8 w = *reinterpret_cast<const bf16x8*>(Wt + (size_t)((cb & 3) * 16 + r16) * 128 + koff);
      acc[0][cb] = __builtin_amdgcn_mfma_f32_16x16x32_bf16(w, x0, acc[0][cb], 0, 0, 0);
      acc[1][cb] = __builtin_amdgcn_mfma_f32_16x16x32_bf16(w, x1, acc[1][cb], 0, 0, 0);
    }
  }

#pragma unroll
  for (int cb = 0; cb < 8; ++cb) {
#pragma unroll
    for (int rb = 0; rb < 2; ++rb) {
      int row = rowBase + rb * 16 + r16;
      if (row < M) {
        f32x4 a = acc[rb][cb];
        if (cb < 4) {
          u32 p = 0;
          p = __builtin_amdgcn_cvt_pk_fp8_f32(a[0], a[1], p, false);
          p = __builtin_amdgcn_cvt_pk_fp8_f32(a[2], a[3], p, true);
          h[(size_t)row * 16 + cb * 4 + kg] = p;
        } else {
          *reinterpret_cast<f32x4*>(g + (size_t)row * 64 + (cb - 4) * 16 + kg * 4) = a;
        }
      }
    }
  }
}

// ---------------- launch ----------------

extern "C" void kernel_launch(void* const* d_in, const int* in_sizes, int n_in,
                              void* d_out, int out_size, void* d_ws, size_t ws_size,
                              hipStream_t stream) {
  const float* x_s = (const float*)d_in[0];
  const float* x_t = (const float*)d_in[1];
  const int* s2t = (const int*)d_in[2];
  const int* t2s = (const int*)d_in[3];
  const float* W1s_l = (const float*)d_in[4];
  const float* W1s_r = (const float*)d_in[5];
  const float* b1s = (const float*)d_in[6];
  const float* W1t_l = (const float*)d_in[7];
  const float* W1t_r = (const float*)d_in[8];
  const float* b1t = (const float*)d_in[9];
  const float* W2s_l = (const float*)d_in[10];
  const float* W2s_r = (const float*)d_in[11];
  const float* b2s = (const float*)d_in[12];
  const float* W2t_l = (const float*)d_in[13];
  const float* W2t_r = (const float*)d_in[14];
  const float* b2t = (const float*)d_in[15];

  const int NS = in_sizes[0] / 128;
  const int NT = in_sizes[1] / 128;
  const int E = in_sizes[2] / 2;

  char* ws = (char*)d_ws;
  size_t off = 0;
  auto alloc = [&](size_t bytes) -> void* {
    void* p = ws + off;
    off = (off + bytes + 255) & ~(size_t)255;
    return p;
  };

  const int nbkS = cdiv(NS, BNODES);
  const int nbkT = cdiv(NT, BNODES);
  const int nblk2 = cdiv(E, EPB2);

  int* gcur = (int*)alloc(2 * NBKT * 4);
  u16* Wt = (u16*)alloc(98304 * 2);
  u32* bktS = (u32*)alloc((size_t)nbkS * CAP * 4);
  u32* bktT = (u32*)alloc((size_t)nbkT * CAP * 4);
  u32* stdegS = (u32*)alloc((size_t)NS * 4);
  u32* stdegT = (u32*)alloc((size_t)NT * 4);

  // R2 ((NS+NT)*512 B): head [0,384B/node) = mean_bf -> h_f8/g; tail [384,512) = fp8 x
  char* R2 = (char*)alloc((size_t)(NS + NT) * 512);
  u16* xnew_s = (u16*)alloc((size_t)(NS + NT) * 256);  // bf16 [*][128]
  u16* xnew_t = xnew_s + (size_t)NS * 128;

  u16* mean_s = (u16*)R2;  // [NS][128] bf16
  u16* mean_t = mean_s + (size_t)NS * 128;
  u32* hs_f8 = (u32*)R2;   // [NS][16] u32 (64 fp8)
  u32* ht_f8 = hs_f8 + (size_t)NS * 16;
  float* g_s = (float*)(ht_f8 + (size_t)NT * 16);
  float* g_t = g_s + (size_t)NS * 64;

  u32* xs_f8 = (u32*)(R2 + (size_t)(NS + NT) * 384);  // [NS][32] u32
  u32* xt_f8 = xs_f8 + (size_t)NS * 32;

  u16* Wt1s_l = Wt;
  u16* Wt1s_r = Wt + 16384;
  u16* Wt1t_l = Wt + 32768;
  u16* Wt1t_r = Wt + 49152;
  u16* Wt2A_s = Wt + 65536;  // W2t_l^T (h_s)
  u16* Wt2B_s = Wt + 73728;  // W2s_r^T (g_s)
  u16* Wt2A_t = Wt + 81920;  // W2s_l^T (h_t)
  u16* Wt2B_t = Wt + 90112;  // W2t_r^T (g_t)

  float* z_s = (float*)d_out;
  float* z_t = (float*)d_out + (size_t)NS * 64;

  // conversions + bucket-cursor reset
  cvt_f8_k<<<cdiv(NS * 32 + NT * 32, 256), 256, 0, stream>>>(
      x_s, x_t, NS * 32, NT * 32, xs_f8, xt_f8);
  cvtW_k<<<48, 256, 0, stream>>>(W1s_l, W1s_r, W1t_l, W1t_r,
                                 W2t_l, W2s_r, W2s_l, W2t_r, Wt);
  hipMemsetAsync(gcur, 0, 2 * NBKT * 4, stream);

  // LDS-staged bucket scatter, both directions
  scatfuse2_k<<<2 * nblk2, 512, 0, stream>>>(t2s, t2s + E, s2t, s2t + E, E, nblk2,
                                             gcur, bktS, bktT);
  // per-bucket sort -> csr + stdeg
  sortb_k<<<nbkS + nbkT, 256, 0, stream>>>(bktS, bktT, gcur, NS, NT, stdegS, stdegT);

  // ----- layer 1 -----
  agg128D_k<<<cdiv(NS, 16) + cdiv(NT, 16), 256, 0, stream>>>(
      xs_f8, xt_f8, bktS, bktT, stdegS, stdegT, NS, NT, (u32*)mean_s, (u32*)mean_t);
  gemm1_dual_k<<<cdiv(NS, 128) + cdiv(NT, 128), 256, 0, stream>>>(
      mean_s, x_s, mean_t, x_t, Wt1s_l, Wt1s_r, Wt1t_l, Wt1t_r,
      b1s, b1t, xnew_s, xnew_t, NS, NT);

  // ----- layer 2 (transform-first) -----
  gemm2_dual_k<<<cdiv(NS, 128) + cdiv(NT, 128), 256, 0, stream>>>(
      xnew_s, xnew_t, Wt2A_s, Wt2B_s, Wt2A_t, Wt2B_t, hs_f8, ht_f8, g_s, g_t, NS, NT);
  agg64D_k<<<cdiv(NS, 16) + cdiv(NT, 16), 256, 0, stream>>>(
      hs_f8, ht_f8, bktS, bktT, stdegS, stdegT, NS, NT,
      g_s, g_t, b2s, b2t, z_s, z_t);
}

// Round 10
// 220.423 us; speedup vs baseline: 1.2442x; 1.0598x over previous
//
#include <hip/hip_runtime.h>

typedef unsigned int u32;
typedef unsigned short u16;
typedef __attribute__((ext_vector_type(4))) float f32x4;
typedef __attribute__((ext_vector_type(2))) float f32x2;
typedef __attribute__((ext_vector_type(8))) short bf16x8;

static inline int cdiv(int a, int b) { return (a + b - 1) / b; }

#define NBKT 512
#define BSHIFT 7
#define BNODES 128
#define EPB2 16384  // edges per scatter block (LDS-staged)
#define CAP 5120    // per-bucket capacity; mean fill ~4096, +16 sigma headroom

// ---------- bf16 helpers ----------
__device__ inline u32 pk_bf16(float a, float b) {
  u32 ua = __builtin_bit_cast(u32, a);
  ua += 0x7fffu + ((ua >> 16) & 1u);
  u32 ub = __builtin_bit_cast(u32, b);
  ub += 0x7fffu + ((ub >> 16) & 1u);
  return (ua >> 16) | (ub & 0xffff0000u);
}

// ---------- fp32 -> fp8 e4m3 (4 elems/thread), both sides fused ----------
__global__ __launch_bounds__(256) void cvt_f8_k(const float* __restrict__ xs,
                                                const float* __restrict__ xt,
                                                int n4S, int n4T,
                                                u32* __restrict__ xsf8,
                                                u32* __restrict__ xtf8) {
  int i = blockIdx.x * 256 + threadIdx.x;
  const float* src;
  u32* dst;
  int q;
  if (i < n4S) {
    src = xs; dst = xsf8; q = i;
  } else {
    q = i - n4S;
    if (q >= n4T) return;
    src = xt; dst = xtf8;
  }
  float4 v = *reinterpret_cast<const float4*>(src + (size_t)q * 4);
  u32 p = 0;
  p = __builtin_amdgcn_cvt_pk_fp8_f32(v.x, v.y, p, false);
  p = __builtin_amdgcn_cvt_pk_fp8_f32(v.z, v.w, p, true);
  dst[q] = p;
}

// ---------- weights -> transposed bf16, packed buffer ----------
__global__ __launch_bounds__(256) void cvtW_k(const float* __restrict__ W1sl,
                                              const float* __restrict__ W1sr,
                                              const float* __restrict__ W1tl,
                                              const float* __restrict__ W1tr,
                                              const float* __restrict__ W2A_s,
                                              const float* __restrict__ W2B_s,
                                              const float* __restrict__ W2A_t,
                                              const float* __restrict__ W2B_t,
                                              u16* __restrict__ out) {
  int seg = blockIdx.x * 256 + threadIdx.x;  // 12288 total, 8 bf16 per seg
  if (seg >= 12288) return;
  const float* W;
  int ncol, base, local;
  if (seg < 8192) {
    int m = seg >> 11; local = seg & 2047; ncol = 128; base = m * 16384;
    W = m == 0 ? W1sl : m == 1 ? W1sr : m == 2 ? W1tl : W1tr;
  } else {
    int m = (seg - 8192) >> 10; local = (seg - 8192) & 1023; ncol = 64; base = 65536 + m * 8192;
    W = m == 0 ? W2A_s : m == 1 ? W2B_s : m == 2 ? W2A_t : W2B_t;
  }
  int col = local >> 4;
  int k0 = (local & 15) * 8;
  u16 tmp[8];
#pragma unroll
  for (int e = 0; e < 8; ++e) {
    float v = W[(size_t)(k0 + e) * ncol + col];
    tmp[e] = (u16)(pk_bf16(v, 0.f) & 0xffffu);
  }
  *reinterpret_cast<uint4*>(out + (size_t)base + col * 128 + k0) =
      *reinterpret_cast<uint4*>(tmp);
}

// ================= LDS-staged bucket scatter =================

__global__ __launch_bounds__(512) void scatfuse2_k(const int* __restrict__ rowS,
                                                   const int* __restrict__ colS,
                                                   const int* __restrict__ rowT,
                                                   const int* __restrict__ colT,
                                                   int E, int nblk,
                                                   int* __restrict__ gcur,
                                                   u32* __restrict__ bktS,
                                                   u32* __restrict__ bktT) {
  __shared__ u32 stage[EPB2];
  __shared__ int h[NBKT], lstart[NBKT], lpos[NBKT], gbase[NBKT];
  int b = blockIdx.x;
  const int *row, *col;
  u32* bkt;
  int* gc;
  if (b < nblk) {
    row = rowS; col = colS; bkt = bktS; gc = gcur;
  } else {
    b -= nblk; row = rowT; col = colT; bkt = bktT; gc = gcur + NBKT;
  }
  int t = threadIdx.x;
  h[t] = 0;  // 512 threads == NBKT
  __syncthreads();
  int base = b * EPB2, end = min(base + EPB2, E);
  for (int i = base + t; i < end; i += 512) atomicAdd(&h[col[i] >> BSHIFT], 1);
  __syncthreads();
  lstart[t] = h[t];
  __syncthreads();
  for (int off = 1; off < NBKT; off <<= 1) {
    int x = (t >= off) ? lstart[t - off] : 0;
    __syncthreads();
    if (t >= off) lstart[t] += x;
    __syncthreads();
  }
  {
    int hc = h[t];
    int ls = lstart[t] - hc;
    lstart[t] = ls;
    lpos[t] = ls;
    gbase[t] = hc ? atomicAdd(&gc[t], hc) : 0;
  }
  __syncthreads();
  for (int i = base + t; i < end; i += 512) {
    int c = col[i];
    int p = atomicAdd(&lpos[c >> BSHIFT], 1);
    stage[p] = ((u32)row[i] << 16) | (u32)c;
  }
  __syncthreads();
  int total = end - base;
  for (int j = t; j < total; j += 512) {
    u32 v = stage[j];
    u32 d = v & 0xffffu;
    int bi = d >> BSHIFT;
    int gp = gbase[bi] + (j - lstart[bi]);
    bkt[(size_t)bi * CAP + gp] = ((v >> 16) << BSHIFT) | (d & (BNODES - 1));
  }
}

// ================= per-bucket sort: bkt -> sorted csr (in place) + stdeg =================

__global__ __launch_bounds__(256) void sortb_k(u32* __restrict__ bktS,
                                               u32* __restrict__ bktT,
                                               const int* __restrict__ gcur,
                                               int NS, int NT,
                                               u32* __restrict__ stdegS,
                                               u32* __restrict__ stdegT) {
  __shared__ u32 srcs[CAP];
  __shared__ int cnt[BNODES], excl[BNODES], st[BNODES], cur[BNODES];
  int nbkS = (NS + BNODES - 1) >> BSHIFT;
  int b = blockIdx.x;
  u32 *bkt, *stdeg;
  int N, ec;
  if (b < nbkS) {
    bkt = bktS + (size_t)b * CAP; ec = gcur[b]; stdeg = stdegS; N = NS;
  } else {
    b -= nbkS;
    bkt = bktT + (size_t)b * CAP; ec = gcur[NBKT + b]; stdeg = stdegT; N = NT;
  }
  int node0 = b << BSHIFT;
  int t = threadIdx.x;
  if (t < BNODES) cnt[t] = 0;
  __syncthreads();
  for (int i = t; i < ec; i += 256) atomicAdd(&cnt[bkt[i] & (BNODES - 1)], 1);
  __syncthreads();
  if (t < BNODES) excl[t] = cnt[t];
  __syncthreads();
  for (int off = 1; off < BNODES; off <<= 1) {
    int x = 0;
    if (t < BNODES && t >= off) x = excl[t - off];
    __syncthreads();
    if (t < BNODES && t >= off) excl[t] += x;
    __syncthreads();
  }
  if (t < BNODES) {
    int s0 = excl[t] - cnt[t];
    st[t] = s0;
    cur[t] = s0;
  }
  __syncthreads();
  for (int i = t; i < ec; i += 256) {
    u32 p = bkt[i];
    int ps = atomicAdd(&cur[p & (BNODES - 1)], 1);
    srcs[ps] = p >> BSHIFT;
  }
  __syncthreads();
  for (int i = t; i < ec; i += 256) bkt[i] = srcs[i];
  if (t < BNODES) {
    int node = node0 + t;
    if (node < N) stdeg[node] = ((u32)st[t] << 16) | (u32)cnt[t];
  }
}

// ================= layer-1 gather: one node / 16-lane group, unroll 8, XCD-split =================
// blockIdx%8 < 4 -> S-destinations (gather x_t); else T-destinations (gather x_s).
// Keeps each direction's 6.4 MB source array resident in its half of the XCDs' L2s.

__global__ __launch_bounds__(256) void agg128D_k(const u32* __restrict__ xs_f8,
                                                 const u32* __restrict__ xt_f8,
                                                 const u32* __restrict__ bktS,
                                                 const u32* __restrict__ bktT,
                                                 const u32* __restrict__ stdegS,
                                                 const u32* __restrict__ stdegT,
                                                 int NS, int NT,
                                                 u32* __restrict__ mean_s,
                                                 u32* __restrict__ mean_t) {
  int nbS = (NS + 15) >> 4;
  int nbT = (NT + 15) >> 4;
  int slot = blockIdx.x & 7;
  int pair = blockIdx.x >> 3;
  int gid = threadIdx.x >> 4, fl = threadIdx.x & 15;
  const u32 *xf8, *bkt, *stdeg;
  u32* outm;
  int N, node;
  if (slot < 4) {
    int blk = pair * 4 + slot;
    if (blk >= nbS) return;
    xf8 = xt_f8; bkt = bktS; stdeg = stdegS; outm = mean_s; N = NS;
    node = blk * 16 + gid;
  } else {
    int blk = pair * 4 + (slot - 4);
    if (blk >= nbT) return;
    xf8 = xs_f8; bkt = bktT; stdeg = stdegT; outm = mean_t; N = NT;
    node = blk * 16 + gid;
  }
  if (node >= N) return;
  u32 sd = stdeg[node];
  int deg = (int)(sd & 0xffffu);
  const u32* csr = bkt + (size_t)(node >> BSHIFT) * CAP + (sd >> 16);
  f32x2 a0 = {0.f, 0.f}, a1 = {0.f, 0.f}, a2 = {0.f, 0.f}, a3 = {0.f, 0.f};
  int i = 0;
  for (; i + 8 <= deg; i += 8) {
    int c[8];
#pragma unroll
    for (int j = 0; j < 8; ++j) c[j] = csr[i + j];
    uint2 v[8];
#pragma unroll
    for (int j = 0; j < 8; ++j)
      v[j] = *reinterpret_cast<const uint2*>(xf8 + (size_t)c[j] * 32 + fl * 2);
#pragma unroll
    for (int j = 0; j < 8; ++j) {
      a0 += __builtin_amdgcn_cvt_pk_f32_fp8(v[j].x, false);
      a1 += __builtin_amdgcn_cvt_pk_f32_fp8(v[j].x, true);
      a2 += __builtin_amdgcn_cvt_pk_f32_fp8(v[j].y, false);
      a3 += __builtin_amdgcn_cvt_pk_f32_fp8(v[j].y, true);
    }
  }
  for (; i + 4 <= deg; i += 4) {
    int c[4];
#pragma unroll
    for (int j = 0; j < 4; ++j) c[j] = csr[i + j];
    uint2 v[4];
#pragma unroll
    for (int j = 0; j < 4; ++j)
      v[j] = *reinterpret_cast<const uint2*>(xf8 + (size_t)c[j] * 32 + fl * 2);
#pragma unroll
    for (int j = 0; j < 4; ++j) {
      a0 += __builtin_amdgcn_cvt_pk_f32_fp8(v[j].x, false);
      a1 += __builtin_amdgcn_cvt_pk_f32_fp8(v[j].x, true);
      a2 += __builtin_amdgcn_cvt_pk_f32_fp8(v[j].y, false);
      a3 += __builtin_amdgcn_cvt_pk_f32_fp8(v[j].y, true);
    }
  }
  for (; i < deg; ++i) {
    int c0 = csr[i];
    uint2 v0 = *reinterpret_cast<const uint2*>(xf8 + (size_t)c0 * 32 + fl * 2);
    a0 += __builtin_amdgcn_cvt_pk_f32_fp8(v0.x, false);
    a1 += __builtin_amdgcn_cvt_pk_f32_fp8(v0.x, true);
    a2 += __builtin_amdgcn_cvt_pk_f32_fp8(v0.y, false);
    a3 += __builtin_amdgcn_cvt_pk_f32_fp8(v0.y, true);
  }
  float inv = deg > 0 ? 1.f / (float)deg : 0.f;
  uint4 p;
  p.x = pk_bf16(a0.x * inv, a0.y * inv);
  p.y = pk_bf16(a1.x * inv, a1.y * inv);
  p.z = pk_bf16(a2.x * inv, a2.y * inv);
  p.w = pk_bf16(a3.x * inv, a3.y * inv);
  *reinterpret_cast<uint4*>(outm + (size_t)node * 64 + fl * 4) = p;
}

// ================= layer-2 gather + epilogue: unroll 8, XCD-split =================

__global__ __launch_bounds__(256) void agg64D_k(const u32* __restrict__ hs_f8,
                                                const u32* __restrict__ ht_f8,
                                                const u32* __restrict__ bktS,
                                                const u32* __restrict__ bktT,
                                                const u32* __restrict__ stdegS,
                                                const u32* __restrict__ stdegT,
                                                int NS, int NT,
                                                const float* __restrict__ g_s,
                                                const float* __restrict__ g_t,
                                                const float* __restrict__ b2s,
                                                const float* __restrict__ b2t,
                                                float* __restrict__ z_s,
                                                float* __restrict__ z_t) {
  int nbS = (NS + 15) >> 4;
  int nbT = (NT + 15) >> 4;
  int slot = blockIdx.x & 7;
  int pair = blockIdx.x >> 3;
  int gid = threadIdx.x >> 4, fl = threadIdx.x & 15;
  const u32 *hf8, *bkt, *stdeg;
  const float *g, *bias;
  float* z;
  int N, node;
  if (slot < 4) {
    int blk = pair * 4 + slot;
    if (blk >= nbS) return;
    hf8 = ht_f8; bkt = bktS; stdeg = stdegS; g = g_s; bias = b2s; z = z_s; N = NS;
    node = blk * 16 + gid;
  } else {
    int blk = pair * 4 + (slot - 4);
    if (blk >= nbT) return;
    hf8 = hs_f8; bkt = bktT; stdeg = stdegT; g = g_t; bias = b2t; z = z_t; N = NT;
    node = blk * 16 + gid;
  }
  if (node >= N) return;
  u32 sd = stdeg[node];
  int deg = (int)(sd & 0xffffu);
  const u32* csr = bkt + (size_t)(node >> BSHIFT) * CAP + (sd >> 16);
  f32x2 a0 = {0.f, 0.f}, a1 = {0.f, 0.f};
  int i = 0;
  for (; i + 8 <= deg; i += 8) {
    int c[8];
#pragma unroll
    for (int j = 0; j < 8; ++j) c[j] = csr[i + j];
    u32 v[8];
#pragma unroll
    for (int j = 0; j < 8; ++j) v[j] = hf8[(size_t)c[j] * 16 + fl];
#pragma unroll
    for (int j = 0; j < 8; ++j) {
      a0 += __builtin_amdgcn_cvt_pk_f32_fp8(v[j], false);
      a1 += __builtin_amdgcn_cvt_pk_f32_fp8(v[j], true);
    }
  }
  for (; i + 4 <= deg; i += 4) {
    int c[4];
#pragma unroll
    for (int j = 0; j < 4; ++j) c[j] = csr[i + j];
    u32 v[4];
#pragma unroll
    for (int j = 0; j < 4; ++j) v[j] = hf8[(size_t)c[j] * 16 + fl];
#pragma unroll
    for (int j = 0; j < 4; ++j) {
      a0 += __builtin_amdgcn_cvt_pk_f32_fp8(v[j], false);
      a1 += __builtin_amdgcn_cvt_pk_f32_fp8(v[j], true);
    }
  }
  for (; i < deg; ++i) {
    u32 v0 = hf8[(size_t)csr[i] * 16 + fl];
    a0 += __builtin_amdgcn_cvt_pk_f32_fp8(v0, false);
    a1 += __builtin_amdgcn_cvt_pk_f32_fp8(v0, true);
  }
  float inv = deg > 0 ? 1.f / (float)deg : 0.f;
  float4 gv = *reinterpret_cast<const float4*>(g + (size_t)node * 64 + fl * 4);
  float4 bv = *reinterpret_cast<const float4*>(bias + fl * 4);
  float4 r;
  r.x = a0.x * inv + gv.x + bv.x;
  r.y = a0.y * inv + gv.y + bv.y;
  r.z = a1.x * inv + gv.z + bv.z;
  r.w = a1.y * inv + gv.w + bv.w;
  *reinterpret_cast<float4*>(z + (size_t)node * 64 + fl * 4) = r;
}

// ---------------- layer-1 MFMA GEMM (dirs fused): xnew_bf16 = [mean|x]@[W0;W1]+bias ----------------

__global__ __launch_bounds__(256) void gemm1_dual_k(
    const u16* __restrict__ mean_s, const float* __restrict__ xs,
    const u16* __restrict__ mean_t, const float* __restrict__ xt,
    const u16* __restrict__ Wt_s0, const u16* __restrict__ Wt_s1,
    const u16* __restrict__ Wt_t0, const u16* __restrict__ Wt_t1,
    const float* __restrict__ b1s, const float* __restrict__ b1t,
    u16* __restrict__ xnew_s, u16* __restrict__ xnew_t, int NS, int NT) {
  int nb1 = (NS + 127) >> 7;
  int b = blockIdx.x;
  const u16 *A0, *Wt0, *Wt1;
  const float *X1, *bias;
  u16* out;
  int M, rowBase;
  if (b < nb1) {
    A0 = mean_s; X1 = xs; Wt0 = Wt_s0; Wt1 = Wt_s1; bias = b1s; out = xnew_s;
    M = NS; rowBase = b * 128;
  } else {
    A0 = mean_t; X1 = xt; Wt0 = Wt_t0; Wt1 = Wt_t1; bias = b1t; out = xnew_t;
    M = NT; rowBase = (b - nb1) * 128;
  }
  const int lane = threadIdx.x & 63;
  const int wid = threadIdx.x >> 6;
  const int r16 = lane & 15;
  const int kg = lane >> 4;
  rowBase += wid * 32;

  f32x4 acc[2][8];
#pragma unroll
  for (int i = 0; i < 2; ++i)
#pragma unroll
    for (int j = 0; j < 8; ++j) acc[i][j] = (f32x4){0.f, 0.f, 0.f, 0.f};

  const int r0 = min(rowBase + r16, M - 1);
  const int r1 = min(rowBase + 16 + r16, M - 1);

#pragma unroll
  for (int ch = 0; ch < 8; ++ch) {
    const int koff = (ch & 3) * 32 + kg * 8;
    bf16x8 x0, x1;
    if (ch < 4) {
      x0 = *reinterpret_cast<const bf16x8*>(A0 + (size_t)r0 * 128 + koff);
      x1 = *reinterpret_cast<const bf16x8*>(A0 + (size_t)r1 * 128 + koff);
    } else {
      float4 fa = *reinterpret_cast<const float4*>(X1 + (size_t)r0 * 128 + koff);
      float4 fb = *reinterpret_cast<const float4*>(X1 + (size_t)r0 * 128 + koff + 4);
      uint4 u0;
      u0.x = pk_bf16(fa.x, fa.y); u0.y = pk_bf16(fa.z, fa.w);
      u0.z = pk_bf16(fb.x, fb.y); u0.w = pk_bf16(fb.z, fb.w);
      x0 = __builtin_bit_cast(bf16x8, u0);
      float4 fc = *reinterpret_cast<const float4*>(X1 + (size_t)r1 * 128 + koff);
      float4 fd = *reinterpret_cast<const float4*>(X1 + (size_t)r1 * 128 + koff + 4);
      uint4 u1;
      u1.x = pk_bf16(fc.x, fc.y); u1.y = pk_bf16(fc.z, fc.w);
      u1.z = pk_bf16(fd.x, fd.y); u1.w = pk_bf16(fd.z, fd.w);
      x1 = __builtin_bit_cast(bf16x8, u1);
    }
    const u16* Wt = (ch < 4) ? Wt0 : Wt1;
#pragma unroll
    for (int cb = 0; cb < 8; ++cb) {
      bf16x8 w = *reinterpret_cast<const bf16x8*>(Wt + (size_t)(cb * 16 + r16) * 128 + koff);
      acc[0][cb] = __builtin_amdgcn_mfma_f32_16x16x32_bf16(w, x0, acc[0][cb], 0, 0, 0);
      acc[1][cb] = __builtin_amdgcn_mfma_f32_16x16x32_bf16(w, x1, acc[1][cb], 0, 0, 0);
    }
  }

#pragma unroll
  for (int cb = 0; cb < 8; ++cb) {
    float4 bv = *reinterpret_cast<const float4*>(bias + cb * 16 + kg * 4);
#pragma unroll
    for (int rb = 0; rb < 2; ++rb) {
      int row = rowBase + rb * 16 + r16;
      if (row < M) {
        f32x4 a = acc[rb][cb];
        uint2 p;
        p.x = pk_bf16(a[0] + bv.x, a[1] + bv.y);
        p.y = pk_bf16(a[2] + bv.z, a[3] + bv.w);
        *reinterpret_cast<uint2*>(out + (size_t)row * 128 + cb * 16 + kg * 4) = p;
      }
    }
  }
}

// ---------------- layer-2 MFMA GEMM (dirs fused): h_fp8 = X@Wa, g_f32 = X@Wb ----------------

__global__ __launch_bounds__(256) void gemm2_dual_k(
    const u16* __restrict__ xnew_s, const u16* __restrict__ xnew_t,
    const u16* __restrict__ WtA_s, const u16* __restrict__ WtB_s,
    const u16* __restrict__ WtA_t, const u16* __restrict__ WtB_t,
    u32* __restrict__ hs_f8, u32* __restrict__ ht_f8,
    float* __restrict__ g_s, float* __restrict__ g_t, int NS, int NT) {
  int nb1 = (NS + 127) >> 7;
  int b = blockIdx.x;
  const u16 *X, *WtA, *WtB;
  u32* h;
  float* g;
  int M, rowBase;
  if (b < nb1) {
    X = xnew_s; WtA = WtA_s; WtB = WtB_s; h = hs_f8; g = g_s; M = NS; rowBase = b * 128;
  } else {
    X = xnew_t; WtA = WtA_t; WtB = WtB_t; h = ht_f8; g = g_t; M = NT;
    rowBase = (b - nb1) * 128;
  }
  const int lane = threadIdx.x & 63;
  const int wid = threadIdx.x >> 6;
  const int r16 = lane & 15;
  const int kg = lane >> 4;
  rowBase += wid * 32;

  f32x4 acc[2][8];
#pragma unroll
  for (int i = 0; i < 2; ++i)
#pragma unroll
    for (int j = 0; j < 8; ++j) acc[i][j] = (f32x4){0.f, 0.f, 0.f, 0.f};

  const int r0 = min(rowBase + r16, M - 1);
  const int r1 = min(rowBase + 16 + r16, M - 1);

#pragma unroll
  for (int ch = 0; ch < 4; ++ch) {
    const int koff = ch * 32 + kg * 8;
    bf16x8 x0 = *reinterpret_cast<const bf16x8*>(X + (size_t)r0 * 128 + koff);
    bf16x8 x1 = *reinterpret_cast<const bf16x8*>(X + (size_t)r1 * 128 + koff);
#pragma unroll
    for (int cb = 0; cb < 8; ++cb) {
      const u16* Wt = (cb < 4) ? WtA : WtB;
      bf16x8 w = *reinterpret_cast<const bf16x8*>(Wt + (size_t)((cb & 3) * 16 + r16) * 128 + koff);
      acc[0][cb] = __builtin_amdgcn_mfma_f32_16x16x32_bf16(w, x0, acc[0][cb], 0, 0, 0);
      acc[1][cb] = __builtin_amdgcn_mfma_f32_16x16x32_bf16(w, x1, acc[1][cb], 0, 0, 0);
    }
  }

#pragma unroll
  for (int cb = 0; cb < 8; ++cb) {
#pragma unroll
    for (int rb = 0; rb < 2; ++rb) {
      int row = rowBase + rb * 16 + r16;
      if (row < M) {
        f32x4 a = acc[rb][cb];
        if (cb < 4) {
          u32 p = 0;
          p = __builtin_amdgcn_cvt_pk_fp8_f32(a[0], a[1], p, false);
          p = __builtin_amdgcn_cvt_pk_fp8_f32(a[2], a[3], p, true);
          h[(size_t)row * 16 + cb * 4 + kg] = p;
        } else {
          *reinterpret_cast<f32x4*>(g + (size_t)row * 64 + (cb - 4) * 16 + kg * 4) = a;
        }
      }
    }
  }
}

// ---------------- launch ----------------

extern "C" void kernel_launch(void* const* d_in, const int* in_sizes, int n_in,
                              void* d_out, int out_size, void* d_ws, size_t ws_size,
                              hipStream_t stream) {
  const float* x_s = (const float*)d_in[0];
  const float* x_t = (const float*)d_in[1];
  const int* s2t = (const int*)d_in[2];
  const int* t2s = (const int*)d_in[3];
  const float* W1s_l = (const float*)d_in[4];
  const float* W1s_r = (const float*)d_in[5];
  const float* b1s = (const float*)d_in[6];
  const float* W1t_l = (const float*)d_in[7];
  const float* W1t_r = (const float*)d_in[8];
  const float* b1t = (const float*)d_in[9];
  const float* W2s_l = (const float*)d_in[10];
  const float* W2s_r = (const float*)d_in[11];
  const float* b2s = (const float*)d_in[12];
  const float* W2t_l = (const float*)d_in[13];
  const float* W2t_r = (const float*)d_in[14];
  const float* b2t = (const float*)d_in[15];

  const int NS = in_sizes[0] / 128;
  const int NT = in_sizes[1] / 128;
  const int E = in_sizes[2] / 2;

  char* ws = (char*)d_ws;
  size_t off = 0;
  auto alloc = [&](size_t bytes) -> void* {
    void* p = ws + off;
    off = (off + bytes + 255) & ~(size_t)255;
    return p;
  };

  const int nbkS = cdiv(NS, BNODES);
  const int nbkT = cdiv(NT, BNODES);
  const int nblk2 = cdiv(E, EPB2);

  int* gcur = (int*)alloc(2 * NBKT * 4);
  u16* Wt = (u16*)alloc(98304 * 2);
  u32* bktS = (u32*)alloc((size_t)nbkS * CAP * 4);
  u32* bktT = (u32*)alloc((size_t)nbkT * CAP * 4);
  u32* stdegS = (u32*)alloc((size_t)NS * 4);
  u32* stdegT = (u32*)alloc((size_t)NT * 4);

  // R2 ((NS+NT)*512 B): head [0,384B/node) = mean_bf -> h_f8/g; tail [384,512) = fp8 x
  char* R2 = (char*)alloc((size_t)(NS + NT) * 512);
  u16* xnew_s = (u16*)alloc((size_t)(NS + NT) * 256);  // bf16 [*][128]
  u16* xnew_t = xnew_s + (size_t)NS * 128;

  u16* mean_s = (u16*)R2;  // [NS][128] bf16
  u16* mean_t = mean_s + (size_t)NS * 128;
  u32* hs_f8 = (u32*)R2;   // [NS][16] u32 (64 fp8)
  u32* ht_f8 = hs_f8 + (size_t)NS * 16;
  float* g_s = (float*)(ht_f8 + (size_t)NT * 16);
  float* g_t = g_s + (size_t)NS * 64;

  u32* xs_f8 = (u32*)(R2 + (size_t)(NS + NT) * 384);  // [NS][32] u32
  u32* xt_f8 = xs_f8 + (size_t)NS * 32;

  u16* Wt1s_l = Wt;
  u16* Wt1s_r = Wt + 16384;
  u16* Wt1t_l = Wt + 32768;
  u16* Wt1t_r = Wt + 49152;
  u16* Wt2A_s = Wt + 65536;  // W2t_l^T (h_s)
  u16* Wt2B_s = Wt + 73728;  // W2s_r^T (g_s)
  u16* Wt2A_t = Wt + 81920;  // W2s_l^T (h_t)
  u16* Wt2B_t = Wt + 90112;  // W2t_r^T (g_t)

  float* z_s = (float*)d_out;
  float* z_t = (float*)d_out + (size_t)NS * 64;

  // conversions + bucket-cursor reset
  cvt_f8_k<<<cdiv(NS * 32 + NT * 32, 256), 256, 0, stream>>>(
      x_s, x_t, NS * 32, NT * 32, xs_f8, xt_f8);
  cvtW_k<<<48, 256, 0, stream>>>(W1s_l, W1s_r, W1t_l, W1t_r,
                                 W2t_l, W2s_r, W2s_l, W2t_r, Wt);
  hipMemsetAsync(gcur, 0, 2 * NBKT * 4, stream);

  // LDS-staged bucket scatter, both directions
  scatfuse2_k<<<2 * nblk2, 512, 0, stream>>>(t2s, t2s + E, s2t, s2t + E, E, nblk2,
                                             gcur, bktS, bktT);
  // per-bucket sort -> csr + stdeg
  sortb_k<<<nbkS + nbkT, 256, 0, stream>>>(bktS, bktT, gcur, NS, NT, stdegS, stdegT);

  // XCD-split agg grids: 8 blocks per "pair" (4 S-slots + 4 T-slots)
  const int npair128 = cdiv(max(cdiv(NS, 16), cdiv(NT, 16)), 4);

  // ----- layer 1 -----
  agg128D_k<<<npair128 * 8, 256, 0, stream>>>(
      xs_f8, xt_f8, bktS, bktT, stdegS, stdegT, NS, NT, (u32*)mean_s, (u32*)mean_t);
  gemm1_dual_k<<<cdiv(NS, 128) + cdiv(NT, 128), 256, 0, stream>>>(
      mean_s, x_s, mean_t, x_t, Wt1s_l, Wt1s_r, Wt1t_l, Wt1t_r,
      b1s, b1t, xnew_s, xnew_t, NS, NT);

  // ----- layer 2 (transform-first) -----
  gemm2_dual_k<<<cdiv(NS, 128) + cdiv(NT, 128), 256, 0, stream>>>(
      xnew_s, xnew_t, Wt2A_s, Wt2B_s, Wt2A_t, Wt2B_t, hs_f8, ht_f8, g_s, g_t, NS, NT);
  agg64D_k<<<npair128 * 8, 256, 0, stream>>>(
      hs_f8, ht_f8, bktS, bktT, stdegS, stdegT, NS, NT,
      g_s, g_t, b2s, b2t, z_s, z_t);
}

// Round 11
// 195.515 us; speedup vs baseline: 1.4027x; 1.1274x over previous
//
#include <hip/hip_runtime.h>

typedef unsigned int u32;
typedef unsigned short u16;
typedef __attribute__((ext_vector_type(4))) float f32x4;
typedef __attribute__((ext_vector_type(2))) float f32x2;
typedef __attribute__((ext_vector_type(8))) short bf16x8;

static inline int cdiv(int a, int b) { return (a + b - 1) / b; }

#define NBKT 512
#define BSHIFT 7
#define BNODES 128
#define EPB2 8192   // edges per scatter block (LDS-staged); 392 blocks, 40KB LDS
#define CAP 5120    // per-bucket capacity; mean fill ~4096, +16 sigma headroom

// ---------- bf16 helpers ----------
__device__ inline u32 pk_bf16(float a, float b) {
  u32 ua = __builtin_bit_cast(u32, a);
  ua += 0x7fffu + ((ua >> 16) & 1u);
  u32 ub = __builtin_bit_cast(u32, b);
  ub += 0x7fffu + ((ub >> 16) & 1u);
  return (ua >> 16) | (ub & 0xffff0000u);
}

// ---------- fused input convert: fp32 -> bf16 + fp8 (4 elems/thread) ----------
__global__ __launch_bounds__(256) void cvt_in_k(const float* __restrict__ xs,
                                                const float* __restrict__ xt,
                                                int n4S, int n4T,
                                                uint2* __restrict__ xsbf,
                                                uint2* __restrict__ xtbf,
                                                u32* __restrict__ xsf8,
                                                u32* __restrict__ xtf8) {
  int i = blockIdx.x * 256 + threadIdx.x;
  const float* src;
  uint2* obf;
  u32* of8;
  int q;
  if (i < n4S) {
    src = xs; obf = xsbf; of8 = xsf8; q = i;
  } else {
    q = i - n4S;
    if (q >= n4T) return;
    src = xt; obf = xtbf; of8 = xtf8;
  }
  float4 v = *reinterpret_cast<const float4*>(src + (size_t)q * 4);
  uint2 b;
  b.x = pk_bf16(v.x, v.y);
  b.y = pk_bf16(v.z, v.w);
  obf[q] = b;
  u32 p = 0;
  p = __builtin_amdgcn_cvt_pk_fp8_f32(v.x, v.y, p, false);
  p = __builtin_amdgcn_cvt_pk_fp8_f32(v.z, v.w, p, true);
  of8[q] = p;
}

// ---------- weights -> transposed bf16, packed buffer ----------
__global__ __launch_bounds__(256) void cvtW_k(const float* __restrict__ W1sl,
                                              const float* __restrict__ W1sr,
                                              const float* __restrict__ W1tl,
                                              const float* __restrict__ W1tr,
                                              const float* __restrict__ W2A_s,
                                              const float* __restrict__ W2B_s,
                                              const float* __restrict__ W2A_t,
                                              const float* __restrict__ W2B_t,
                                              u16* __restrict__ out) {
  int seg = blockIdx.x * 256 + threadIdx.x;  // 12288 total, 8 bf16 per seg
  if (seg >= 12288) return;
  const float* W;
  int ncol, base, local;
  if (seg < 8192) {
    int m = seg >> 11; local = seg & 2047; ncol = 128; base = m * 16384;
    W = m == 0 ? W1sl : m == 1 ? W1sr : m == 2 ? W1tl : W1tr;
  } else {
    int m = (seg - 8192) >> 10; local = (seg - 8192) & 1023; ncol = 64; base = 65536 + m * 8192;
    W = m == 0 ? W2A_s : m == 1 ? W2B_s : m == 2 ? W2A_t : W2B_t;
  }
  int col = local >> 4;
  int k0 = (local & 15) * 8;
  u16 tmp[8];
#pragma unroll
  for (int e = 0; e < 8; ++e) {
    float v = W[(size_t)(k0 + e) * ncol + col];
    tmp[e] = (u16)(pk_bf16(v, 0.f) & 0xffffu);
  }
  *reinterpret_cast<uint4*>(out + (size_t)base + col * 128 + k0) =
      *reinterpret_cast<uint4*>(tmp);
}

// ================= LDS-staged bucket scatter =================

__global__ __launch_bounds__(512) void scatfuse2_k(const int* __restrict__ rowS,
                                                   const int* __restrict__ colS,
                                                   const int* __restrict__ rowT,
                                                   const int* __restrict__ colT,
                                                   int E, int nblk,
                                                   int* __restrict__ gcur,
                                                   u32* __restrict__ bktS,
                                                   u32* __restrict__ bktT) {
  __shared__ u32 stage[EPB2];
  __shared__ int h[NBKT], lstart[NBKT], lpos[NBKT], gbase[NBKT];
  int b = blockIdx.x;
  const int *row, *col;
  u32* bkt;
  int* gc;
  if (b < nblk) {
    row = rowS; col = colS; bkt = bktS; gc = gcur;
  } else {
    b -= nblk; row = rowT; col = colT; bkt = bktT; gc = gcur + NBKT;
  }
  int t = threadIdx.x;
  h[t] = 0;  // 512 threads == NBKT
  __syncthreads();
  int base = b * EPB2, end = min(base + EPB2, E);
  for (int i = base + t; i < end; i += 512) atomicAdd(&h[col[i] >> BSHIFT], 1);
  __syncthreads();
  lstart[t] = h[t];
  __syncthreads();
  for (int off = 1; off < NBKT; off <<= 1) {
    int x = (t >= off) ? lstart[t - off] : 0;
    __syncthreads();
    if (t >= off) lstart[t] += x;
    __syncthreads();
  }
  {
    int hc = h[t];
    int ls = lstart[t] - hc;
    lstart[t] = ls;
    lpos[t] = ls;
    gbase[t] = hc ? atomicAdd(&gc[t], hc) : 0;
  }
  __syncthreads();
  for (int i = base + t; i < end; i += 512) {
    int c = col[i];
    int p = atomicAdd(&lpos[c >> BSHIFT], 1);
    stage[p] = ((u32)row[i] << 16) | (u32)c;
  }
  __syncthreads();
  int total = end - base;
  for (int j = t; j < total; j += 512) {
    u32 v = stage[j];
    u32 d = v & 0xffffu;
    int bi = d >> BSHIFT;
    int gp = gbase[bi] + (j - lstart[bi]);
    bkt[(size_t)bi * CAP + gp] = ((v >> 16) << BSHIFT) | (d & (BNODES - 1));
  }
}

// ================= per-bucket sort: bkt -> sorted csr (in place) + stdeg =================

__global__ __launch_bounds__(256) void sortb_k(u32* __restrict__ bktS,
                                               u32* __restrict__ bktT,
                                               const int* __restrict__ gcur,
                                               int NS, int NT,
                                               u32* __restrict__ stdegS,
                                               u32* __restrict__ stdegT) {
  __shared__ u32 srcs[CAP];
  __shared__ int cnt[BNODES], excl[BNODES], st[BNODES], cur[BNODES];
  int nbkS = (NS + BNODES - 1) >> BSHIFT;
  int b = blockIdx.x;
  u32 *bkt, *stdeg;
  int N, ec;
  if (b < nbkS) {
    bkt = bktS + (size_t)b * CAP; ec = gcur[b]; stdeg = stdegS; N = NS;
  } else {
    b -= nbkS;
    bkt = bktT + (size_t)b * CAP; ec = gcur[NBKT + b]; stdeg = stdegT; N = NT;
  }
  int node0 = b << BSHIFT;
  int t = threadIdx.x;
  if (t < BNODES) cnt[t] = 0;
  __syncthreads();
  for (int i = t; i < ec; i += 256) atomicAdd(&cnt[bkt[i] & (BNODES - 1)], 1);
  __syncthreads();
  if (t < BNODES) excl[t] = cnt[t];
  __syncthreads();
  for (int off = 1; off < BNODES; off <<= 1) {
    int x = 0;
    if (t < BNODES && t >= off) x = excl[t - off];
    __syncthreads();
    if (t < BNODES && t >= off) excl[t] += x;
    __syncthreads();
  }
  if (t < BNODES) {
    int s0 = excl[t] - cnt[t];
    st[t] = s0;
    cur[t] = s0;
  }
  __syncthreads();
  for (int i = t; i < ec; i += 256) {
    u32 p = bkt[i];
    int ps = atomicAdd(&cur[p & (BNODES - 1)], 1);
    srcs[ps] = p >> BSHIFT;
  }
  __syncthreads();
  for (int i = t; i < ec; i += 256) bkt[i] = srcs[i];
  if (t < BNODES) {
    int node = node0 + t;
    if (node < N) stdeg[node] = ((u32)st[t] << 16) | (u32)cnt[t];
  }
}

// ================= layer-1 gather: one node / 16-lane group, unroll 8, XCD-split =================

__global__ __launch_bounds__(256) void agg128D_k(const u32* __restrict__ xs_f8,
                                                 const u32* __restrict__ xt_f8,
                                                 const u32* __restrict__ bktS,
                                                 const u32* __restrict__ bktT,
                                                 const u32* __restrict__ stdegS,
                                                 const u32* __restrict__ stdegT,
                                                 int NS, int NT,
                                                 u32* __restrict__ mean_s,
                                                 u32* __restrict__ mean_t) {
  int nbS = (NS + 15) >> 4;
  int nbT = (NT + 15) >> 4;
  int slot = blockIdx.x & 7;
  int pair = blockIdx.x >> 3;
  int gid = threadIdx.x >> 4, fl = threadIdx.x & 15;
  const u32 *xf8, *bkt, *stdeg;
  u32* outm;
  int N, node;
  if (slot < 4) {
    int blk = pair * 4 + slot;
    if (blk >= nbS) return;
    xf8 = xt_f8; bkt = bktS; stdeg = stdegS; outm = mean_s; N = NS;
    node = blk * 16 + gid;
  } else {
    int blk = pair * 4 + (slot - 4);
    if (blk >= nbT) return;
    xf8 = xs_f8; bkt = bktT; stdeg = stdegT; outm = mean_t; N = NT;
    node = blk * 16 + gid;
  }
  if (node >= N) return;
  u32 sd = stdeg[node];
  int deg = (int)(sd & 0xffffu);
  const u32* csr = bkt + (size_t)(node >> BSHIFT) * CAP + (sd >> 16);
  f32x2 a0 = {0.f, 0.f}, a1 = {0.f, 0.f}, a2 = {0.f, 0.f}, a3 = {0.f, 0.f};
  int i = 0;
  for (; i + 8 <= deg; i += 8) {
    int c[8];
#pragma unroll
    for (int j = 0; j < 8; ++j) c[j] = csr[i + j];
    uint2 v[8];
#pragma unroll
    for (int j = 0; j < 8; ++j)
      v[j] = *reinterpret_cast<const uint2*>(xf8 + (size_t)c[j] * 32 + fl * 2);
#pragma unroll
    for (int j = 0; j < 8; ++j) {
      a0 += __builtin_amdgcn_cvt_pk_f32_fp8(v[j].x, false);
      a1 += __builtin_amdgcn_cvt_pk_f32_fp8(v[j].x, true);
      a2 += __builtin_amdgcn_cvt_pk_f32_fp8(v[j].y, false);
      a3 += __builtin_amdgcn_cvt_pk_f32_fp8(v[j].y, true);
    }
  }
  for (; i + 4 <= deg; i += 4) {
    int c[4];
#pragma unroll
    for (int j = 0; j < 4; ++j) c[j] = csr[i + j];
    uint2 v[4];
#pragma unroll
    for (int j = 0; j < 4; ++j)
      v[j] = *reinterpret_cast<const uint2*>(xf8 + (size_t)c[j] * 32 + fl * 2);
#pragma unroll
    for (int j = 0; j < 4; ++j) {
      a0 += __builtin_amdgcn_cvt_pk_f32_fp8(v[j].x, false);
      a1 += __builtin_amdgcn_cvt_pk_f32_fp8(v[j].x, true);
      a2 += __builtin_amdgcn_cvt_pk_f32_fp8(v[j].y, false);
      a3 += __builtin_amdgcn_cvt_pk_f32_fp8(v[j].y, true);
    }
  }
  for (; i < deg; ++i) {
    int c0 = csr[i];
    uint2 v0 = *reinterpret_cast<const uint2*>(xf8 + (size_t)c0 * 32 + fl * 2);
    a0 += __builtin_amdgcn_cvt_pk_f32_fp8(v0.x, false);
    a1 += __builtin_amdgcn_cvt_pk_f32_fp8(v0.x, true);
    a2 += __builtin_amdgcn_cvt_pk_f32_fp8(v0.y, false);
    a3 += __builtin_amdgcn_cvt_pk_f32_fp8(v0.y, true);
  }
  float inv = deg > 0 ? 1.f / (float)deg : 0.f;
  uint4 p;
  p.x = pk_bf16(a0.x * inv, a0.y * inv);
  p.y = pk_bf16(a1.x * inv, a1.y * inv);
  p.z = pk_bf16(a2.x * inv, a2.y * inv);
  p.w = pk_bf16(a3.x * inv, a3.y * inv);
  *reinterpret_cast<uint4*>(outm + (size_t)node * 64 + fl * 4) = p;
}

// ================= layer-2 gather + epilogue: unroll 8, XCD-split =================

__global__ __launch_bounds__(256) void agg64D_k(const u32* __restrict__ hs_f8,
                                                const u32* __restrict__ ht_f8,
                                                const u32* __restrict__ bktS,
                                                const u32* __restrict__ bktT,
                                                const u32* __restrict__ stdegS,
                                                const u32* __restrict__ stdegT,
                                                int NS, int NT,
                                                const float* __restrict__ g_s,
                                                const float* __restrict__ g_t,
                                                const float* __restrict__ b2s,
                                                const float* __restrict__ b2t,
                                                float* __restrict__ z_s,
                                                float* __restrict__ z_t) {
  int nbS = (NS + 15) >> 4;
  int nbT = (NT + 15) >> 4;
  int slot = blockIdx.x & 7;
  int pair = blockIdx.x >> 3;
  int gid = threadIdx.x >> 4, fl = threadIdx.x & 15;
  const u32 *hf8, *bkt, *stdeg;
  const float *g, *bias;
  float* z;
  int N, node;
  if (slot < 4) {
    int blk = pair * 4 + slot;
    if (blk >= nbS) return;
    hf8 = ht_f8; bkt = bktS; stdeg = stdegS; g = g_s; bias = b2s; z = z_s; N = NS;
    node = blk * 16 + gid;
  } else {
    int blk = pair * 4 + (slot - 4);
    if (blk >= nbT) return;
    hf8 = hs_f8; bkt = bktT; stdeg = stdegT; g = g_t; bias = b2t; z = z_t; N = NT;
    node = blk * 16 + gid;
  }
  if (node >= N) return;
  u32 sd = stdeg[node];
  int deg = (int)(sd & 0xffffu);
  const u32* csr = bkt + (size_t)(node >> BSHIFT) * CAP + (sd >> 16);
  f32x2 a0 = {0.f, 0.f}, a1 = {0.f, 0.f};
  int i = 0;
  for (; i + 8 <= deg; i += 8) {
    int c[8];
#pragma unroll
    for (int j = 0; j < 8; ++j) c[j] = csr[i + j];
    u32 v[8];
#pragma unroll
    for (int j = 0; j < 8; ++j) v[j] = hf8[(size_t)c[j] * 16 + fl];
#pragma unroll
    for (int j = 0; j < 8; ++j) {
      a0 += __builtin_amdgcn_cvt_pk_f32_fp8(v[j], false);
      a1 += __builtin_amdgcn_cvt_pk_f32_fp8(v[j], true);
    }
  }
  for (; i + 4 <= deg; i += 4) {
    int c[4];
#pragma unroll
    for (int j = 0; j < 4; ++j) c[j] = csr[i + j];
    u32 v[4];
#pragma unroll
    for (int j = 0; j < 4; ++j) v[j] = hf8[(size_t)c[j] * 16 + fl];
#pragma unroll
    for (int j = 0; j < 4; ++j) {
      a0 += __builtin_amdgcn_cvt_pk_f32_fp8(v[j], false);
      a1 += __builtin_amdgcn_cvt_pk_f32_fp8(v[j], true);
    }
  }
  for (; i < deg; ++i) {
    u32 v0 = hf8[(size_t)csr[i] * 16 + fl];
    a0 += __builtin_amdgcn_cvt_pk_f32_fp8(v0, false);
    a1 += __builtin_amdgcn_cvt_pk_f32_fp8(v0, true);
  }
  float inv = deg > 0 ? 1.f / (float)deg : 0.f;
  float4 gv = *reinterpret_cast<const float4*>(g + (size_t)node * 64 + fl * 4);
  float4 bv = *reinterpret_cast<const float4*>(bias + fl * 4);
  float4 r;
  r.x = a0.x * inv + gv.x + bv.x;
  r.y = a0.y * inv + gv.y + bv.y;
  r.z = a1.x * inv + gv.z + bv.z;
  r.w = a1.y * inv + gv.w + bv.w;
  *reinterpret_cast<float4*>(z + (size_t)node * 64 + fl * 4) = r;
}

// ---------------- layer-1 MFMA GEMM: 64 rows/wave (4 frags), cb halved ----------------
// xnew_bf16 = [mean | x_bf] @ [W0;W1] + bias.  256 rows/block.

__global__ __launch_bounds__(256) void gemm1_dual_k(
    const u16* __restrict__ mean_s, const u16* __restrict__ xs_bf,
    const u16* __restrict__ mean_t, const u16* __restrict__ xt_bf,
    const u16* __restrict__ Wt_s0, const u16* __restrict__ Wt_s1,
    const u16* __restrict__ Wt_t0, const u16* __restrict__ Wt_t1,
    const float* __restrict__ b1s, const float* __restrict__ b1t,
    u16* __restrict__ xnew_s, u16* __restrict__ xnew_t, int NS, int NT) {
  int nb1 = (NS + 255) >> 8;
  int b = blockIdx.x;
  const u16 *A0, *A1, *Wt0, *Wt1;
  const float* bias;
  u16* out;
  int M, rowBase;
  if (b < nb1) {
    A0 = mean_s; A1 = xs_bf; Wt0 = Wt_s0; Wt1 = Wt_s1; bias = b1s; out = xnew_s;
    M = NS; rowBase = b * 256;
  } else {
    A0 = mean_t; A1 = xt_bf; Wt0 = Wt_t0; Wt1 = Wt_t1; bias = b1t; out = xnew_t;
    M = NT; rowBase = (b - nb1) * 256;
  }
  const int lane = threadIdx.x & 63;
  const int wid = threadIdx.x >> 6;
  const int r16 = lane & 15;
  const int kg = lane >> 4;
  rowBase += wid * 64;

  int r[4];
#pragma unroll
  for (int f = 0; f < 4; ++f) r[f] = min(rowBase + f * 16 + r16, M - 1);

#pragma unroll
  for (int cbh = 0; cbh < 2; ++cbh) {
    f32x4 acc[4][4];
#pragma unroll
    for (int f = 0; f < 4; ++f)
#pragma unroll
      for (int j = 0; j < 4; ++j) acc[f][j] = (f32x4){0.f, 0.f, 0.f, 0.f};

#pragma unroll
    for (int ch = 0; ch < 8; ++ch) {
      const u16* A = (ch < 4) ? A0 : A1;
      const u16* Wt = (ch < 4) ? Wt0 : Wt1;
      const int koff = (ch & 3) * 32 + kg * 8;
      bf16x8 x[4];
#pragma unroll
      for (int f = 0; f < 4; ++f)
        x[f] = *reinterpret_cast<const bf16x8*>(A + (size_t)r[f] * 128 + koff);
#pragma unroll
      for (int cb = 0; cb < 4; ++cb) {
        int cbg = cbh * 4 + cb;
        bf16x8 w = *reinterpret_cast<const bf16x8*>(Wt + (size_t)(cbg * 16 + r16) * 128 + koff);
#pragma unroll
        for (int f = 0; f < 4; ++f)
          acc[f][cb] = __builtin_amdgcn_mfma_f32_16x16x32_bf16(w, x[f], acc[f][cb], 0, 0, 0);
      }
    }

#pragma unroll
    for (int cb = 0; cb < 4; ++cb) {
      int cbg = cbh * 4 + cb;
      float4 bv = *reinterpret_cast<const float4*>(bias + cbg * 16 + kg * 4);
#pragma unroll
      for (int f = 0; f < 4; ++f) {
        int row = rowBase + f * 16 + r16;
        if (row < M) {
          f32x4 a = acc[f][cb];
          uint2 p;
          p.x = pk_bf16(a[0] + bv.x, a[1] + bv.y);
          p.y = pk_bf16(a[2] + bv.z, a[3] + bv.w);
          *reinterpret_cast<uint2*>(out + (size_t)row * 128 + cbg * 16 + kg * 4) = p;
        }
      }
    }
  }
}

// ---------------- layer-2 MFMA GEMM: 64 rows/wave (4 frags) ----------------
// h_fp8 = X@Wa (cbh=0), g_f32 = X@Wb (cbh=1).

__global__ __launch_bounds__(256) void gemm2_dual_k(
    const u16* __restrict__ xnew_s, const u16* __restrict__ xnew_t,
    const u16* __restrict__ WtA_s, const u16* __restrict__ WtB_s,
    const u16* __restrict__ WtA_t, const u16* __restrict__ WtB_t,
    u32* __restrict__ hs_f8, u32* __restrict__ ht_f8,
    float* __restrict__ g_s, float* __restrict__ g_t, int NS, int NT) {
  int nb1 = (NS + 255) >> 8;
  int b = blockIdx.x;
  const u16 *X, *WtA, *WtB;
  u32* h;
  float* g;
  int M, rowBase;
  if (b < nb1) {
    X = xnew_s; WtA = WtA_s; WtB = WtB_s; h = hs_f8; g = g_s; M = NS; rowBase = b * 256;
  } else {
    X = xnew_t; WtA = WtA_t; WtB = WtB_t; h = ht_f8; g = g_t; M = NT;
    rowBase = (b - nb1) * 256;
  }
  const int lane = threadIdx.x & 63;
  const int wid = threadIdx.x >> 6;
  const int r16 = lane & 15;
  const int kg = lane >> 4;
  rowBase += wid * 64;

  int r[4];
#pragma unroll
  for (int f = 0; f < 4; ++f) r[f] = min(rowBase + f * 16 + r16, M - 1);

#pragma unroll
  for (int cbh = 0; cbh < 2; ++cbh) {
    const u16* Wt = (cbh == 0) ? WtA : WtB;
    f32x4 acc[4][4];
#pragma unroll
    for (int f = 0; f < 4; ++f)
#pragma unroll
      for (int j = 0; j < 4; ++j) acc[f][j] = (f32x4){0.f, 0.f, 0.f, 0.f};

#pragma unroll
    for (int ch = 0; ch < 4; ++ch) {
      const int koff = ch * 32 + kg * 8;
      bf16x8 x[4];
#pragma unroll
      for (int f = 0; f < 4; ++f)
        x[f] = *reinterpret_cast<const bf16x8*>(X + (size_t)r[f] * 128 + koff);
#pragma unroll
      for (int cb = 0; cb < 4; ++cb) {
        bf16x8 w = *reinterpret_cast<const bf16x8*>(Wt + (size_t)(cb * 16 + r16) * 128 + koff);
#pragma unroll
        for (int f = 0; f < 4; ++f)
          acc[f][cb] = __builtin_amdgcn_mfma_f32_16x16x32_bf16(w, x[f], acc[f][cb], 0, 0, 0);
      }
    }

#pragma unroll
    for (int cb = 0; cb < 4; ++cb) {
#pragma unroll
      for (int f = 0; f < 4; ++f) {
        int row = rowBase + f * 16 + r16;
        if (row < M) {
          f32x4 a = acc[f][cb];
          if (cbh == 0) {
            u32 p = 0;
            p = __builtin_amdgcn_cvt_pk_fp8_f32(a[0], a[1], p, false);
            p = __builtin_amdgcn_cvt_pk_fp8_f32(a[2], a[3], p, true);
            h[(size_t)row * 16 + cb * 4 + kg] = p;
          } else {
            *reinterpret_cast<f32x4*>(g + (size_t)row * 64 + cb * 16 + kg * 4) = a;
          }
        }
      }
    }
  }
}

// ---------------- launch ----------------

extern "C" void kernel_launch(void* const* d_in, const int* in_sizes, int n_in,
                              void* d_out, int out_size, void* d_ws, size_t ws_size,
                              hipStream_t stream) {
  const float* x_s = (const float*)d_in[0];
  const float* x_t = (const float*)d_in[1];
  const int* s2t = (const int*)d_in[2];
  const int* t2s = (const int*)d_in[3];
  const float* W1s_l = (const float*)d_in[4];
  const float* W1s_r = (const float*)d_in[5];
  const float* b1s = (const float*)d_in[6];
  const float* W1t_l = (const float*)d_in[7];
  const float* W1t_r = (const float*)d_in[8];
  const float* b1t = (const float*)d_in[9];
  const float* W2s_l = (const float*)d_in[10];
  const float* W2s_r = (const float*)d_in[11];
  const float* b2s = (const float*)d_in[12];
  const float* W2t_l = (const float*)d_in[13];
  const float* W2t_r = (const float*)d_in[14];
  const float* b2t = (const float*)d_in[15];

  const int NS = in_sizes[0] / 128;
  const int NT = in_sizes[1] / 128;
  const int E = in_sizes[2] / 2;

  char* ws = (char*)d_ws;
  size_t off = 0;
  auto alloc = [&](size_t bytes) -> void* {
    void* p = ws + off;
    off = (off + bytes + 255) & ~(size_t)255;
    return p;
  };

  const int nbkS = cdiv(NS, BNODES);
  const int nbkT = cdiv(NT, BNODES);
  const int nblk2 = cdiv(E, EPB2);

  int* gcur = (int*)alloc(2 * NBKT * 4);
  u16* Wt = (u16*)alloc(98304 * 2);
  u32* bktS = (u32*)alloc((size_t)nbkS * CAP * 4);
  u32* bktT = (u32*)alloc((size_t)nbkT * CAP * 4);
  u32* stdegS = (u32*)alloc((size_t)NS * 4);
  u32* stdegT = (u32*)alloc((size_t)NT * 4);

  // R2 ((NS+NT)*512 B): head [0,384B/node) = mean_bf -> h_f8/g; tail [384,512) = fp8 x
  char* R2 = (char*)alloc((size_t)(NS + NT) * 512);
  u16* xnew_s = (u16*)alloc((size_t)(NS + NT) * 256);  // bf16 [*][128]
  u16* xnew_t = xnew_s + (size_t)NS * 128;
  u16* xs_bf = (u16*)alloc((size_t)(NS + NT) * 256);   // bf16 x copies
  u16* xt_bf = xs_bf + (size_t)NS * 128;

  u16* mean_s = (u16*)R2;  // [NS][128] bf16
  u16* mean_t = mean_s + (size_t)NS * 128;
  u32* hs_f8 = (u32*)R2;   // [NS][16] u32 (64 fp8)
  u32* ht_f8 = hs_f8 + (size_t)NS * 16;
  float* g_s = (float*)(ht_f8 + (size_t)NT * 16);
  float* g_t = g_s + (size_t)NS * 64;

  u32* xs_f8 = (u32*)(R2 + (size_t)(NS + NT) * 384);  // [NS][32] u32
  u32* xt_f8 = xs_f8 + (size_t)NS * 32;

  u16* Wt1s_l = Wt;
  u16* Wt1s_r = Wt + 16384;
  u16* Wt1t_l = Wt + 32768;
  u16* Wt1t_r = Wt + 49152;
  u16* Wt2A_s = Wt + 65536;  // W2t_l^T (h_s)
  u16* Wt2B_s = Wt + 73728;  // W2s_r^T (g_s)
  u16* Wt2A_t = Wt + 81920;  // W2s_l^T (h_t)
  u16* Wt2B_t = Wt + 90112;  // W2t_r^T (g_t)

  float* z_s = (float*)d_out;
  float* z_t = (float*)d_out + (size_t)NS * 64;

  // conversions + bucket-cursor reset
  cvt_in_k<<<cdiv(NS * 32 + NT * 32, 256), 256, 0, stream>>>(
      x_s, x_t, NS * 32, NT * 32, (uint2*)xs_bf, (uint2*)xt_bf, xs_f8, xt_f8);
  cvtW_k<<<48, 256, 0, stream>>>(W1s_l, W1s_r, W1t_l, W1t_r,
                                 W2t_l, W2s_r, W2s_l, W2t_r, Wt);
  hipMemsetAsync(gcur, 0, 2 * NBKT * 4, stream);

  // LDS-staged bucket scatter, both directions
  scatfuse2_k<<<2 * nblk2, 512, 0, stream>>>(t2s, t2s + E, s2t, s2t + E, E, nblk2,
                                             gcur, bktS, bktT);
  // per-bucket sort -> csr + stdeg
  sortb_k<<<nbkS + nbkT, 256, 0, stream>>>(bktS, bktT, gcur, NS, NT, stdegS, stdegT);

  // XCD-split agg grids: 8 blocks per "pair" (4 S-slots + 4 T-slots)
  const int npair128 = cdiv(max(cdiv(NS, 16), cdiv(NT, 16)), 4);

  // ----- layer 1 -----
  agg128D_k<<<npair128 * 8, 256, 0, stream>>>(
      xs_f8, xt_f8, bktS, bktT, stdegS, stdegT, NS, NT, (u32*)mean_s, (u32*)mean_t);
  gemm1_dual_k<<<cdiv(NS, 256) + cdiv(NT, 256), 256, 0, stream>>>(
      mean_s, xs_bf, mean_t, xt_bf, Wt1s_l, Wt1s_r, Wt1t_l, Wt1t_r,
      b1s, b1t, xnew_s, xnew_t, NS, NT);

  // ----- layer 2 (transform-first) -----
  gemm2_dual_k<<<cdiv(NS, 256) + cdiv(NT, 256), 256, 0, stream>>>(
      xnew_s, xnew_t, Wt2A_s, Wt2B_s, Wt2A_t, Wt2B_t, hs_f8, ht_f8, g_s, g_t, NS, NT);
  agg64D_k<<<npair128 * 8, 256, 0, stream>>>(
      hs_f8, ht_f8, bktS, bktT, stdegS, stdegT, NS, NT,
      g_s, g_t, b2s, b2t, z_s, z_t);
}